// Round 12
// baseline (204.740 us; speedup 1.0000x reference)
//
#include <hip/hip_runtime.h>

#define N_NODES 10000
#define E_EDGES 320000
#define HDIM    256
#define NG      20
#define BN_EPS  1e-5f

typedef __attribute__((ext_vector_type(8))) short short8;
typedef __attribute__((ext_vector_type(4))) float f32x4;

__device__ __forceinline__ float silu_f(float v) {
    float e = __expf(-v);
    return v * __builtin_amdgcn_rcpf(1.0f + e);
}

__device__ __forceinline__ unsigned int cvt_pk(float lo, float hi) {
    unsigned int r;
    asm("v_cvt_pk_bf16_f32 %0, %1, %2" : "=v"(r) : "v"(lo), "v"(hi));
    return r;
}

__device__ __forceinline__ unsigned short f2bf(float f) {
    union { float f; unsigned int u; } v; v.f = f;
    unsigned int r = v.u + 0x7fffu + ((v.u >> 16) & 1u);   // RNE
    return (unsigned short)(r >> 16);
}

__device__ __forceinline__ f32x4 bf4_to_f32(uint2 u) {
    union { unsigned int i; float f; } a, b, c, d;
    a.i = u.x << 16; b.i = u.x & 0xFFFF0000u;
    c.i = u.y << 16; d.i = u.y & 0xFFFF0000u;
    return (f32x4){a.f, b.f, c.f, d.f};
}

// ---------------------------------------------------------------------------
// Fused prep: weight packing + edge histogram + x -> bf16 cast.
// ---------------------------------------------------------------------------
__global__ __launch_bounds__(256) void prep_hist_kernel(
    const float* __restrict__ Wf2, const float* __restrict__ Wu1,
    const float* __restrict__ Wu2, const float* __restrict__ Wf1,
    const float* __restrict__ bf1, const int* __restrict__ ei_row,
    const float* __restrict__ x,
    unsigned short* __restrict__ Pf2, unsigned short* __restrict__ Pu1,
    unsigned short* __restrict__ Pu2, unsigned short* __restrict__ P1,
    int* __restrict__ cnt, unsigned short* __restrict__ xb)
{
    const int bx = blockIdx.x;
    if (bx >= 2050) {
        const int idx = ((bx - 2050) * 256 + threadIdx.x) * 8;
        const float4* s = (const float4*)(x + idx);
        float4 a = s[0], b = s[1];
        *(uint4*)(xb + idx) = make_uint4(cvt_pk(a.x, a.y), cvt_pk(a.z, a.w),
                                         cvt_pk(b.x, b.y), cvt_pk(b.z, b.w));
        return;
    }
    if (bx >= 800) {
        int e = (bx - 800) * 256 + threadIdx.x;
        atomicAdd(&cnt[ei_row[e]], 1);
        return;
    }
    int tid = bx * 256 + threadIdx.x;
    if (tid < 196608) {
        int which = tid >> 16, local = tid & 65535;
        const float* W = (which == 0) ? Wf2 : (which == 1) ? Wu1 : Wu2;
        unsigned short* P = (which == 0) ? Pf2 : (which == 1) ? Pu1 : Pu2;
        int j = local & 7, lane = (local >> 3) & 63;
        int ntile = (local >> 9) & 15, kstep = local >> 13;
        int k = kstep * 32 + (lane >> 4) * 8 + j;
        int n = ntile * 16 + (lane & 15);
        P[local] = f2bf(W[k * 256 + n]);
    } else {
        int local = tid - 196608;   // 0..8191
        int j = local & 7, lane = (local >> 3) & 63, ntile = local >> 9;
        int k = (lane >> 4) * 8 + j;
        int n = ntile * 16 + (lane & 15);
        float v = (k < NG) ? Wf1[k * 256 + n] : (k == NG ? bf1[n] : 0.0f);
        P1[local] = f2bf(v);
    }
}

// ---------------------------------------------------------------------------
// CSR build: scan + fill (fill packs edge id + col into one int2 store)
// ---------------------------------------------------------------------------
__global__ __launch_bounds__(256) void scan_kernel(int* __restrict__ cnt) {
    __shared__ int tot[256];
    const int t = threadIdx.x;
    int loc[40];
    int s = 0;
    #pragma unroll
    for (int i = 0; i < 40; ++i) { loc[i] = cnt[t * 40 + i]; s += loc[i]; }
    tot[t] = s;
    __syncthreads();
    for (int off = 1; off < 256; off <<= 1) {
        int u = (t >= off) ? tot[t - off] : 0;
        __syncthreads();
        tot[t] += u;
        __syncthreads();
    }
    int pre = tot[t] - s;
    #pragma unroll
    for (int i = 0; i < 40; ++i) { int v = loc[i]; cnt[t * 40 + i] = pre; pre += v; }
}

__global__ __launch_bounds__(256) void fill_kernel(const int* __restrict__ ei_row,
                                                   const int* __restrict__ ei_col,
                                                   int* __restrict__ cnt,
                                                   int2* __restrict__ pc,
                                                   int* __restrict__ nodepos) {
    int e = blockIdx.x * 256 + threadIdx.x;
    int r = ei_row[e];
    int c = ei_col[e];
    int pos = atomicAdd(&cnt[r], 1);
    pc[pos] = make_int2(e, c);
    nodepos[pos] = r;
}

// ---------------------------------------------------------------------------
// Edge kernel: 64 CSR-ordered edges / block, 8 waves (512 thr), 4 blocks/CU
// (32 waves/CU: LDS 4x38400=153.6KB, VGPR<=64).
// GEMM1 (swapped): hiddenT = Wf1T.rbfT; rbf staged once in LDS (80B rows).
// GEMM2 (swapped): filtT = Wf2T.hiddenT; A-frags streamed from L2 packed W.
// msg = (filt+bf2)*xb[col] stored bf16 (single pass, all 64 rows).
// Reduce: 512 threads = 256 cols x 2 halves of 32 rows; 8-deep batched LDS
// loads; boundary segment merged via a 2KB LDS stash; contiguous per-node-row
// atomics into agg.
// ---------------------------------------------------------------------------
#define SM_NID 0        // 64 int (256 B)
#define SM_RBF 256      // [64][40] ushort rows of 80 B (5120 B); stash overlay
#define SM_HID 5376     // 32768 B: hid bf16 [64][256] swz / msg bf16 overlay
#define SM_TOT 38144

__global__ __launch_bounds__(512, 8) void edge_kernel(
    const float* __restrict__ rbf, const int2* __restrict__ pc,
    const int* __restrict__ nodepos,
    const unsigned short* __restrict__ P1, const unsigned short* __restrict__ P2,
    const float* __restrict__ bf2, const unsigned short* __restrict__ xb,
    float* __restrict__ agg)
{
    __shared__ char sm[SM_TOT];
    int* nid_s = (int*)(sm + SM_NID);

    const int t = threadIdx.x;
    int blk = blockIdx.x;
    blk = (blk & 7) * 625 + (blk >> 3);   // XCD swizzle (5000 = 8*625, bijective)
    const int p0 = blk * 64;
    const int l = t & 63, w = t >> 6;
    const int l15 = l & 15, l4 = l >> 4;

    if (t < 64) nid_s[t] = nodepos[p0 + t];
    // rbf -> LDS bf16, 80 B rows; k=20 bias row (1.0), 21..31 zero
    if (t < 128) {
        const int row = t >> 1, half = t & 1;
        const float* rp = rbf + (size_t)pc[p0 + row].x * NG + half * 10;
        float v[10];
        if (half == 0) {
            float4 a = *(const float4*)rp, b = *(const float4*)(rp + 4);
            float2 c = *(const float2*)(rp + 8);
            v[0]=a.x; v[1]=a.y; v[2]=a.z; v[3]=a.w; v[4]=b.x;
            v[5]=b.y; v[6]=b.z; v[7]=b.w; v[8]=c.x; v[9]=c.y;
        } else {
            float2 a = *(const float2*)rp;
            float4 b = *(const float4*)(rp + 2), c = *(const float4*)(rp + 6);
            v[0]=a.x; v[1]=a.y; v[2]=b.x; v[3]=b.y; v[4]=b.z;
            v[5]=b.w; v[6]=c.x; v[7]=c.y; v[8]=c.z; v[9]=c.w;
        }
        unsigned int* dst = (unsigned int*)(sm + SM_RBF + row * 80 + half * 20);
        #pragma unroll
        for (int i = 0; i < 5; ++i) dst[i] = cvt_pk(v[2*i], v[2*i+1]);
    } else if (t < 192) {
        const int row = t - 128;
        *(unsigned long long*)(sm + SM_RBF + row * 80 + 40) = 0x3F80ull; // 1.0,0,0,0
        *(uint4*)(sm + SM_RBF + row * 80 + 48) = make_uint4(0, 0, 0, 0);
    }

    // per-thread edge columns (packed with edge id, no dependent gather)
    int colp[4];
    #pragma unroll
    for (int nt = 0; nt < 4; ++nt) colp[nt] = pc[p0 + nt * 16 + l15].y;

    // GEMM1 A-frags (Wf1T) and GEMM2 ks=0 A-frags (Wf2T): wave owns tiles 2w,2w+1
    short8 a1[2], acur[2];
    #pragma unroll
    for (int mt = 0; mt < 2; ++mt) {
        a1[mt]   = *(const short8*)(P1 + ((2 * w + mt) * 64 + l) * 8);
        acur[mt] = *(const short8*)(P2 + ((2 * w + mt) * 64 + l) * 8);
    }

    __syncthreads();

    f32x4 acc[2][4];   // [mt][nt]
    #pragma unroll
    for (int mt = 0; mt < 2; ++mt)
        #pragma unroll
        for (int nt = 0; nt < 4; ++nt) acc[mt][nt] = (f32x4)0.0f;

    // GEMM1: one K=32 step; B = rbfT from LDS (stride 80B)
    #pragma unroll
    for (int nt = 0; nt < 4; ++nt) {
        short8 bfr = *(const short8*)(sm + SM_RBF + (nt * 16 + l15) * 80 + l4 * 16);
        #pragma unroll
        for (int mt = 0; mt < 2; ++mt)
            acc[mt][nt] = __builtin_amdgcn_mfma_f32_16x16x32_bf16(a1[mt], bfr, acc[mt][nt], 0, 0, 0);
    }

    // silu -> hid bf16, XOR-swizzled, b64 stores
    #pragma unroll
    for (int mt = 0; mt < 2; ++mt) {
        const int hc0 = w * 32 + mt * 16 + l4 * 4;
        #pragma unroll
        for (int nt = 0; nt < 4; ++nt) {
            const int row = nt * 16 + l15;
            unsigned int pk0 = cvt_pk(silu_f(acc[mt][nt][0]), silu_f(acc[mt][nt][1]));
            unsigned int pk1 = cvt_pk(silu_f(acc[mt][nt][2]), silu_f(acc[mt][nt][3]));
            *(uint2*)(sm + SM_HID + row * 512 +
                      (((hc0 >> 3) ^ (row & 7)) << 4) + (hc0 & 7) * 2) =
                make_uint2(pk0, pk1);
        }
    }
    __syncthreads();

    // GEMM2: filtT = Wf2T.hiddenT
    #pragma unroll
    for (int mt = 0; mt < 2; ++mt)
        #pragma unroll
        for (int nt = 0; nt < 4; ++nt) acc[mt][nt] = (f32x4)0.0f;

    for (int ks = 0; ks < 8; ++ks) {
        short8 anext[2];
        if (ks < 7) {
            #pragma unroll
            for (int mt = 0; mt < 2; ++mt)
                anext[mt] = *(const short8*)(P2 + (((ks + 1) * 16 + 2 * w + mt) * 64 + l) * 8);
        }
        #pragma unroll
        for (int nt = 0; nt < 4; ++nt) {
            const int row = nt * 16 + l15;
            short8 bfh = *(const short8*)(sm + SM_HID + row * 512 +
                            ((((ks << 2) + l4) ^ (row & 7)) << 4));
            #pragma unroll
            for (int mt = 0; mt < 2; ++mt)
                acc[mt][nt] = __builtin_amdgcn_mfma_f32_16x16x32_bf16(acur[mt], bfh, acc[mt][nt], 0, 0, 0);
        }
        if (ks < 7) {
            #pragma unroll
            for (int mt = 0; mt < 2; ++mt) acur[mt] = anext[mt];
        }
    }

    // bf16 x gather (5MB table, ~L2/L3 resident)
    uint2 xv[2][4];
    #pragma unroll
    for (int mt = 0; mt < 2; ++mt) {
        const int fc0 = w * 32 + mt * 16 + l4 * 4;
        #pragma unroll
        for (int nt = 0; nt < 4; ++nt)
            xv[mt][nt] = *(const uint2*)(xb + (size_t)colp[nt] * HDIM + fc0);
    }

    f32x4 bc2[2];
    #pragma unroll
    for (int mt = 0; mt < 2; ++mt)
        bc2[mt] = *(const f32x4*)(bf2 + w * 32 + mt * 16 + l4 * 4);

    __syncthreads();   // all hid reads done -> msg overlay

    // msg = (filt+bias)*x -> bf16 LDS, single pass over all 64 rows
    #pragma unroll
    for (int mt = 0; mt < 2; ++mt) {
        const int fc0 = w * 32 + mt * 16 + l4 * 4;
        #pragma unroll
        for (int nt = 0; nt < 4; ++nt) {
            const int row = nt * 16 + l15;
            f32x4 m = (acc[mt][nt] + bc2[mt]) * bf4_to_f32(xv[mt][nt]);
            *(uint2*)(sm + SM_HID + row * 512 +
                      (((fc0 >> 3) ^ (row & 7)) << 4) + (fc0 & 7) * 2) =
                make_uint2(cvt_pk(m[0], m[1]), cvt_pk(m[2], m[3]));
        }
    }
    __syncthreads();

    // segmented reduce: 512 threads = 256 cols x 2 halves of 32 rows.
    // 8-deep batched LDS loads; boundary segment merged via LDS stash.
    {
        const int col = t & 255;
        const int h   = t >> 8;
        const int base = h * 32;
        int* stash_nid   = (int*)(sm + SM_RBF);            // 1 KB (rbf dead)
        float* stash_sum = (float*)(sm + SM_RBF + 1024);   // 1 KB

        float sum = 0.0f;
        int cur = nid_s[base];
        int fnid = 0; float fsum = 0.0f;
        bool held = false;

        #pragma unroll
        for (int c = 0; c < 4; ++c) {
            float v[8];
            #pragma unroll
            for (int i = 0; i < 8; ++i) {
                const int pos = base + c * 8 + i;
                unsigned short u = *(const unsigned short*)(sm + SM_HID + pos * 512 +
                                    (((col >> 3) ^ (pos & 7)) << 4) + (col & 7) * 2);
                union { unsigned int ii; float f; } cv; cv.ii = ((unsigned int)u) << 16;
                v[i] = cv.f;
            }
            #pragma unroll
            for (int i = 0; i < 8; ++i) {
                const int nid = nid_s[base + c * 8 + i];
                if (nid != cur) {
                    if (h == 1 && !held) { fnid = cur; fsum = sum; held = true; }
                    else atomicAdd(&agg[(size_t)cur * HDIM + col], sum);
                    sum = 0.0f; cur = nid;
                }
                sum += v[i];
            }
        }
        if (h == 0) {
            stash_nid[col] = cur; stash_sum[col] = sum;
        } else {
            if (!held) { fnid = cur; fsum = sum; }
            else atomicAdd(&agg[(size_t)cur * HDIM + col], sum);
        }
        __syncthreads();
        if (h == 1) {
            int n0 = stash_nid[col]; float s0 = stash_sum[col];
            if (n0 == fnid) {
                atomicAdd(&agg[(size_t)n0 * HDIM + col], s0 + fsum);
            } else {
                atomicAdd(&agg[(size_t)n0 * HDIM + col], s0);
                atomicAdd(&agg[(size_t)fnid * HDIM + col], fsum);
            }
        }
    }
}

// ---------------------------------------------------------------------------
// Node kernel: 64 rows/block, 512 threads (8 waves, wave owns 32 cols),
// both GEMMs swapped, fused BN partials. LDS 32KB.
// ---------------------------------------------------------------------------
__global__ __launch_bounds__(512, 2) void node_kernel(
    const float* __restrict__ agg, const float* __restrict__ bu1,
    const float* __restrict__ bu2,
    const unsigned short* __restrict__ Pu1, const unsigned short* __restrict__ Pu2,
    float* __restrict__ hout, float* __restrict__ sums)
{
    __shared__ char sm[32768];    // [64 nodes][256] bf16, XOR-swizzled
    const int t  = threadIdx.x;
    const int r0 = blockIdx.x * 64;
    const int l = t & 63, w = t >> 6;        // 8 waves
    const int l15 = l & 15, l4 = l >> 4;

    // stage agg -> LDS bf16 (8 threads/row, 8 float4 each)
    {
        const int row = t & 63, q = t >> 6;
        const bool valid = (r0 + row) < N_NODES;
        const float4* src = (const float4*)(agg + (size_t)(r0 + row) * HDIM) + q * 8;
        #pragma unroll
        for (int i = 0; i < 8; ++i) {
            float4 v = valid ? src[i] : make_float4(0.f, 0.f, 0.f, 0.f);
            const int c0 = q * 32 + i * 4;
            *(uint2*)(sm + row * 512 + (((c0 >> 3) ^ (row & 7)) << 4) + (c0 & 7) * 2) =
                make_uint2(cvt_pk(v.x, v.y), cvt_pk(v.z, v.w));
        }
    }

    short8 acur[2];
    #pragma unroll
    for (int mt = 0; mt < 2; ++mt)
        acur[mt] = *(const short8*)(Pu1 + ((2 * w + mt) * 64 + l) * 8);

    __syncthreads();

    f32x4 acc[2][4];
    #pragma unroll
    for (int mt = 0; mt < 2; ++mt)
        #pragma unroll
        for (int nt = 0; nt < 4; ++nt) acc[mt][nt] = (f32x4)0.0f;

    // GEMM1': midT = Wu1T.aggT
    for (int ks = 0; ks < 8; ++ks) {
        short8 anext[2];
        if (ks < 7) {
            #pragma unroll
            for (int mt = 0; mt < 2; ++mt)
                anext[mt] = *(const short8*)(Pu1 + (((ks + 1) * 16 + 2 * w + mt) * 64 + l) * 8);
        }
        #pragma unroll
        for (int nt = 0; nt < 4; ++nt) {
            const int row = nt * 16 + l15;
            short8 bfa = *(const short8*)(sm + row * 512 +
                            ((((ks << 2) + l4) ^ (row & 7)) << 4));
            #pragma unroll
            for (int mt = 0; mt < 2; ++mt)
                acc[mt][nt] = __builtin_amdgcn_mfma_f32_16x16x32_bf16(acur[mt], bfa, acc[mt][nt], 0, 0, 0);
        }
        if (ks < 7) {
            #pragma unroll
            for (int mt = 0; mt < 2; ++mt) acur[mt] = anext[mt];
        }
    }
    __syncthreads();   // all reads done; overwrite with mid

    #pragma unroll
    for (int mt = 0; mt < 2; ++mt)
        acur[mt] = *(const short8*)(Pu2 + ((2 * w + mt) * 64 + l) * 8);

    // mid = silu(acc + bu1) -> LDS (b64 stores)
    #pragma unroll
    for (int mt = 0; mt < 2; ++mt) {
        const int mc0 = w * 32 + mt * 16 + l4 * 4;
        f32x4 b4 = *(const f32x4*)(bu1 + mc0);
        #pragma unroll
        for (int nt = 0; nt < 4; ++nt) {
            const int row = nt * 16 + l15;
            unsigned int pk0 = cvt_pk(silu_f(acc[mt][nt][0] + b4[0]), silu_f(acc[mt][nt][1] + b4[1]));
            unsigned int pk1 = cvt_pk(silu_f(acc[mt][nt][2] + b4[2]), silu_f(acc[mt][nt][3] + b4[3]));
            *(uint2*)(sm + row * 512 + (((mc0 >> 3) ^ (row & 7)) << 4) + (mc0 & 7) * 2) =
                make_uint2(pk0, pk1);
            acc[mt][nt] = (f32x4)0.0f;
        }
    }
    __syncthreads();

    // GEMM2': hT = Wu2T.midT
    for (int ks = 0; ks < 8; ++ks) {
        short8 anext[2];
        if (ks < 7) {
            #pragma unroll
            for (int mt = 0; mt < 2; ++mt)
                anext[mt] = *(const short8*)(Pu2 + (((ks + 1) * 16 + 2 * w + mt) * 64 + l) * 8);
        }
        #pragma unroll
        for (int nt = 0; nt < 4; ++nt) {
            const int row = nt * 16 + l15;
            short8 bfm = *(const short8*)(sm + row * 512 +
                            ((((ks << 2) + l4) ^ (row & 7)) << 4));
            #pragma unroll
            for (int mt = 0; mt < 2; ++mt)
                acc[mt][nt] = __builtin_amdgcn_mfma_f32_16x16x32_bf16(acur[mt], bfm, acc[mt][nt], 0, 0, 0);
        }
        if (ks < 7) {
            #pragma unroll
            for (int mt = 0; mt < 2; ++mt) acur[mt] = anext[mt];
        }
    }

    // epilogue: float4 h stores + BN partials
    #pragma unroll
    for (int mt = 0; mt < 2; ++mt) {
        const int hc0 = w * 32 + mt * 16 + l4 * 4;
        f32x4 b4 = *(const f32x4*)(bu2 + hc0);
        f32x4 s = (f32x4)0.0f, s2 = (f32x4)0.0f;
        #pragma unroll
        for (int nt = 0; nt < 4; ++nt) {
            const int gr = r0 + nt * 16 + l15;
            if (gr < N_NODES) {
                f32x4 hv = acc[mt][nt] + b4;
                *(f32x4*)(hout + (size_t)gr * HDIM + hc0) = hv;
                s += hv; s2 += hv * hv;
            }
        }
        #pragma unroll
        for (int off = 1; off < 16; off <<= 1) {
            #pragma unroll
            for (int r = 0; r < 4; ++r) {
                s[r]  += __shfl_xor(s[r], off);
                s2[r] += __shfl_xor(s2[r], off);
            }
        }
        if (l15 == 0) {
            #pragma unroll
            for (int r = 0; r < 4; ++r) {
                atomicAdd(&sums[hc0 + r], s[r]);
                atomicAdd(&sums[HDIM + hc0 + r], s2[r]);
            }
        }
    }
}

// ---------------------------------------------------------------------------
__global__ __launch_bounds__(256) void final_kernel(
    const float* __restrict__ x, const float* __restrict__ sums,
    const float* __restrict__ gamma, const float* __restrict__ beta,
    float* __restrict__ out)
{
    const int i4 = blockIdx.x * 256 + threadIdx.x;   // float4 index
    const int j  = (i4 & 63) * 4;
    f32x4 mean = *(const f32x4*)(sums + j) * (1.0f / N_NODES);
    f32x4 s2   = *(const f32x4*)(sums + HDIM + j) * (1.0f / N_NODES);
    f32x4 g    = *(const f32x4*)(gamma + j);
    f32x4 b    = *(const f32x4*)(beta + j);
    f32x4 hv   = ((f32x4*)out)[i4];
    f32x4 xv   = ((const f32x4*)x)[i4];
    f32x4 var  = s2 - mean * mean;
    f32x4 inv;
    #pragma unroll
    for (int r = 0; r < 4; ++r) inv[r] = rsqrtf(var[r] + BN_EPS);
    ((f32x4*)out)[i4] = xv + g * (hv - mean) * inv + b;
}

extern "C" void kernel_launch(void* const* d_in, const int* in_sizes, int n_in,
                              void* d_out, int out_size, void* d_ws, size_t ws_size,
                              hipStream_t stream) {
    const float* x     = (const float*)d_in[0];
    const float* rbf   = (const float*)d_in[1];
    const int*   ei    = (const int*)d_in[2];
    const float* Wf1   = (const float*)d_in[3];
    const float* bf1   = (const float*)d_in[4];
    const float* Wf2   = (const float*)d_in[5];
    const float* bf2   = (const float*)d_in[6];
    const float* Wu1   = (const float*)d_in[7];
    const float* bu1   = (const float*)d_in[8];
    const float* Wu2   = (const float*)d_in[9];
    const float* bu2   = (const float*)d_in[10];
    const float* gamma = (const float*)d_in[11];
    const float* beta  = (const float*)d_in[12];
    float* out = (float*)d_out;

    char* ws = (char*)d_ws;
    float* agg     = (float*)(ws);                            // 10,240,000 B
    float* sums    = (float*)(ws + 10240000);                 // 2,048 B
    int*   cnt     = (int*)(ws + 10242048);                   // 40,960 B
    int*   nodepos = (int*)(ws + 10283008);                   // 1,280,000 B
    unsigned short* Pf2 = (unsigned short*)(ws + 11563008);   // 131,072 B
    unsigned short* Pu1 = (unsigned short*)(ws + 11694080);   // 131,072 B
    unsigned short* Pu2 = (unsigned short*)(ws + 11825152);   // 131,072 B
    unsigned short* P1  = (unsigned short*)(ws + 11956224);   // 16,384 B

    // d_out scratch (fully overwritten by node_kernel afterwards):
    //   [0, 5.12MB): bf16 x    [5.12MB, 7.68MB): packed {edge, col} int2
    unsigned short* xb = (unsigned short*)d_out;
    int2* pc = (int2*)((char*)d_out + 5120000);

    // one memset covers agg + sums + cnt (contiguous)
    hipMemsetAsync(agg, 0, 10283008, stream);

    prep_hist_kernel<<<3300, 256, 0, stream>>>(Wf2, Wu1, Wu2, Wf1, bf1, ei, x,
                                               Pf2, Pu1, Pu2, P1, cnt, xb);
    scan_kernel<<<1, 256, 0, stream>>>(cnt);
    fill_kernel<<<E_EDGES / 256, 256, 0, stream>>>(ei, ei + E_EDGES, cnt,
                                                   pc, nodepos);

    edge_kernel<<<E_EDGES / 64, 512, 0, stream>>>(
        rbf, pc, nodepos, P1, Pf2, bf2, xb, agg);
    node_kernel<<<(N_NODES + 63) / 64, 512, 0, stream>>>(
        agg, bu1, bu2, Pu1, Pu2, out, sums);
    final_kernel<<<(N_NODES * HDIM / 4) / 256, 256, 0, stream>>>(
        x, sums, gamma, beta, out);
}

// Round 13
// 195.574 us; speedup vs baseline: 1.0469x; 1.0469x over previous
//
#include <hip/hip_runtime.h>

#define N_NODES 10000
#define E_EDGES 320000
#define HDIM    256
#define NG      20
#define BN_EPS  1e-5f
#define RB      32    // node rows per block (313 blocks)

typedef __attribute__((ext_vector_type(8))) short short8;
typedef __attribute__((ext_vector_type(4))) float f32x4;

__device__ __forceinline__ float silu_f(float v) {
    float e = __expf(-v);
    return v * __builtin_amdgcn_rcpf(1.0f + e);
}

__device__ __forceinline__ unsigned int cvt_pk(float lo, float hi) {
    unsigned int r;
    asm("v_cvt_pk_bf16_f32 %0, %1, %2" : "=v"(r) : "v"(lo), "v"(hi));
    return r;
}

__device__ __forceinline__ unsigned short f2bf(float f) {
    union { float f; unsigned int u; } v; v.f = f;
    unsigned int r = v.u + 0x7fffu + ((v.u >> 16) & 1u);   // RNE
    return (unsigned short)(r >> 16);
}

__device__ __forceinline__ f32x4 bf4_to_f32(uint2 u) {
    union { unsigned int i; float f; } a, b, c, d;
    a.i = u.x << 16; b.i = u.x & 0xFFFF0000u;
    c.i = u.y << 16; d.i = u.y & 0xFFFF0000u;
    return (f32x4){a.f, b.f, c.f, d.f};
}

// ---------------------------------------------------------------------------
// Fused prep: weight packing + edge histogram + x -> bf16 cast.
// ---------------------------------------------------------------------------
__global__ __launch_bounds__(256) void prep_hist_kernel(
    const float* __restrict__ Wf2, const float* __restrict__ Wu1,
    const float* __restrict__ Wu2, const float* __restrict__ Wf1,
    const float* __restrict__ bf1, const int* __restrict__ ei_row,
    const float* __restrict__ x,
    unsigned short* __restrict__ Pf2, unsigned short* __restrict__ Pu1,
    unsigned short* __restrict__ Pu2, unsigned short* __restrict__ P1,
    int* __restrict__ cnt, unsigned short* __restrict__ xb)
{
    const int bx = blockIdx.x;
    if (bx >= 2050) {
        const int idx = ((bx - 2050) * 256 + threadIdx.x) * 8;
        const float4* s = (const float4*)(x + idx);
        float4 a = s[0], b = s[1];
        *(uint4*)(xb + idx) = make_uint4(cvt_pk(a.x, a.y), cvt_pk(a.z, a.w),
                                         cvt_pk(b.x, b.y), cvt_pk(b.z, b.w));
        return;
    }
    if (bx >= 800) {
        int e = (bx - 800) * 256 + threadIdx.x;
        atomicAdd(&cnt[ei_row[e]], 1);
        return;
    }
    int tid = bx * 256 + threadIdx.x;
    if (tid < 196608) {
        int which = tid >> 16, local = tid & 65535;
        const float* W = (which == 0) ? Wf2 : (which == 1) ? Wu1 : Wu2;
        unsigned short* P = (which == 0) ? Pf2 : (which == 1) ? Pu1 : Pu2;
        int j = local & 7, lane = (local >> 3) & 63;
        int ntile = (local >> 9) & 15, kstep = local >> 13;
        int k = kstep * 32 + (lane >> 4) * 8 + j;
        int n = ntile * 16 + (lane & 15);
        P[local] = f2bf(W[k * 256 + n]);
    } else {
        int local = tid - 196608;   // 0..8191
        int j = local & 7, lane = (local >> 3) & 63, ntile = local >> 9;
        int k = (lane >> 4) * 8 + j;
        int n = ntile * 16 + (lane & 15);
        float v = (k < NG) ? Wf1[k * 256 + n] : (k == NG ? bf1[n] : 0.0f);
        P1[local] = f2bf(v);
    }
}

// ---------------------------------------------------------------------------
// CSR build: scan + fill (fill packs edge id + col into one int2 store)
// ---------------------------------------------------------------------------
__global__ __launch_bounds__(256) void scan_kernel(int* __restrict__ cnt) {
    __shared__ int tot[256];
    const int t = threadIdx.x;
    int loc[40];
    int s = 0;
    #pragma unroll
    for (int i = 0; i < 40; ++i) { loc[i] = cnt[t * 40 + i]; s += loc[i]; }
    tot[t] = s;
    __syncthreads();
    for (int off = 1; off < 256; off <<= 1) {
        int u = (t >= off) ? tot[t - off] : 0;
        __syncthreads();
        tot[t] += u;
        __syncthreads();
    }
    int pre = tot[t] - s;
    #pragma unroll
    for (int i = 0; i < 40; ++i) { int v = loc[i]; cnt[t * 40 + i] = pre; pre += v; }
}

__global__ __launch_bounds__(256) void fill_kernel(const int* __restrict__ ei_row,
                                                   const int* __restrict__ ei_col,
                                                   int* __restrict__ cnt,
                                                   int2* __restrict__ pc,
                                                   int* __restrict__ nodepos) {
    int e = blockIdx.x * 256 + threadIdx.x;
    int r = ei_row[e];
    int c = ei_col[e];
    int pos = atomicAdd(&cnt[r], 1);
    pc[pos] = make_int2(e, c);
    nodepos[pos] = r;
}

// ---------------------------------------------------------------------------
// Edge kernel: 64 CSR-ordered edges / block, 8 waves (512 thr), 3 blocks/CU
// ((512,6): VGPR 40 + 32 acc fits; (512,8) forced spills in r12).
// GEMM1 (swapped): hiddenT = Wf1T.rbfT; rbf staged once in LDS (80B rows).
// GEMM2 (swapped): filtT = Wf2T.hiddenT; A-frags streamed from L2 packed W.
// msg = (filt+bf2)*xb[col] stored bf16 (single pass, all 64 rows).
// Reduce: 512 threads = 256 cols x 2 halves of 32 rows; 8-deep batched LDS
// loads; boundary segment merged via a 2KB LDS stash; contiguous per-node-row
// atomics into agg.
// ---------------------------------------------------------------------------
#define SM_NID 0        // 64 int (256 B)
#define SM_RBF 256      // [64][40] ushort rows of 80 B (5120 B); stash overlay
#define SM_HID 5376     // 32768 B: hid bf16 [64][256] swz / msg bf16 overlay
#define SM_TOT 38144

__global__ __launch_bounds__(512, 6) void edge_kernel(
    const float* __restrict__ rbf, const int2* __restrict__ pc,
    const int* __restrict__ nodepos,
    const unsigned short* __restrict__ P1, const unsigned short* __restrict__ P2,
    const float* __restrict__ bf2, const unsigned short* __restrict__ xb,
    float* __restrict__ agg)
{
    __shared__ char sm[SM_TOT];
    int* nid_s = (int*)(sm + SM_NID);

    const int t = threadIdx.x;
    int blk = blockIdx.x;
    blk = (blk & 7) * 625 + (blk >> 3);   // XCD swizzle (5000 = 8*625, bijective)
    const int p0 = blk * 64;
    const int l = t & 63, w = t >> 6;
    const int l15 = l & 15, l4 = l >> 4;

    if (t < 64) nid_s[t] = nodepos[p0 + t];
    // rbf -> LDS bf16, 80 B rows; k=20 bias row (1.0), 21..31 zero
    if (t < 128) {
        const int row = t >> 1, half = t & 1;
        const float* rp = rbf + (size_t)pc[p0 + row].x * NG + half * 10;
        float v[10];
        if (half == 0) {
            float4 a = *(const float4*)rp, b = *(const float4*)(rp + 4);
            float2 c = *(const float2*)(rp + 8);
            v[0]=a.x; v[1]=a.y; v[2]=a.z; v[3]=a.w; v[4]=b.x;
            v[5]=b.y; v[6]=b.z; v[7]=b.w; v[8]=c.x; v[9]=c.y;
        } else {
            float2 a = *(const float2*)rp;
            float4 b = *(const float4*)(rp + 2), c = *(const float4*)(rp + 6);
            v[0]=a.x; v[1]=a.y; v[2]=b.x; v[3]=b.y; v[4]=b.z;
            v[5]=b.w; v[6]=c.x; v[7]=c.y; v[8]=c.z; v[9]=c.w;
        }
        unsigned int* dst = (unsigned int*)(sm + SM_RBF + row * 80 + half * 20);
        #pragma unroll
        for (int i = 0; i < 5; ++i) dst[i] = cvt_pk(v[2*i], v[2*i+1]);
    } else if (t < 192) {
        const int row = t - 128;
        *(unsigned long long*)(sm + SM_RBF + row * 80 + 40) = 0x3F80ull; // 1.0,0,0,0
        *(uint4*)(sm + SM_RBF + row * 80 + 48) = make_uint4(0, 0, 0, 0);
    }

    // per-thread edge columns (packed with edge id, no dependent gather)
    int colp[4];
    #pragma unroll
    for (int nt = 0; nt < 4; ++nt) colp[nt] = pc[p0 + nt * 16 + l15].y;

    // GEMM1 A-frags (Wf1T) and GEMM2 ks=0 A-frags (Wf2T): wave owns tiles 2w,2w+1
    short8 a1[2], acur[2];
    #pragma unroll
    for (int mt = 0; mt < 2; ++mt) {
        a1[mt]   = *(const short8*)(P1 + ((2 * w + mt) * 64 + l) * 8);
        acur[mt] = *(const short8*)(P2 + ((2 * w + mt) * 64 + l) * 8);
    }

    __syncthreads();

    f32x4 acc[2][4];   // [mt][nt]
    #pragma unroll
    for (int mt = 0; mt < 2; ++mt)
        #pragma unroll
        for (int nt = 0; nt < 4; ++nt) acc[mt][nt] = (f32x4)0.0f;

    // GEMM1: one K=32 step; B = rbfT from LDS (stride 80B)
    #pragma unroll
    for (int nt = 0; nt < 4; ++nt) {
        short8 bfr = *(const short8*)(sm + SM_RBF + (nt * 16 + l15) * 80 + l4 * 16);
        #pragma unroll
        for (int mt = 0; mt < 2; ++mt)
            acc[mt][nt] = __builtin_amdgcn_mfma_f32_16x16x32_bf16(a1[mt], bfr, acc[mt][nt], 0, 0, 0);
    }

    // silu -> hid bf16, XOR-swizzled, b64 stores
    #pragma unroll
    for (int mt = 0; mt < 2; ++mt) {
        const int hc0 = w * 32 + mt * 16 + l4 * 4;
        #pragma unroll
        for (int nt = 0; nt < 4; ++nt) {
            const int row = nt * 16 + l15;
            unsigned int pk0 = cvt_pk(silu_f(acc[mt][nt][0]), silu_f(acc[mt][nt][1]));
            unsigned int pk1 = cvt_pk(silu_f(acc[mt][nt][2]), silu_f(acc[mt][nt][3]));
            *(uint2*)(sm + SM_HID + row * 512 +
                      (((hc0 >> 3) ^ (row & 7)) << 4) + (hc0 & 7) * 2) =
                make_uint2(pk0, pk1);
        }
    }
    __syncthreads();

    // GEMM2: filtT = Wf2T.hiddenT
    #pragma unroll
    for (int mt = 0; mt < 2; ++mt)
        #pragma unroll
        for (int nt = 0; nt < 4; ++nt) acc[mt][nt] = (f32x4)0.0f;

    for (int ks = 0; ks < 8; ++ks) {
        short8 anext[2];
        if (ks < 7) {
            #pragma unroll
            for (int mt = 0; mt < 2; ++mt)
                anext[mt] = *(const short8*)(P2 + (((ks + 1) * 16 + 2 * w + mt) * 64 + l) * 8);
        }
        #pragma unroll
        for (int nt = 0; nt < 4; ++nt) {
            const int row = nt * 16 + l15;
            short8 bfh = *(const short8*)(sm + SM_HID + row * 512 +
                            ((((ks << 2) + l4) ^ (row & 7)) << 4));
            #pragma unroll
            for (int mt = 0; mt < 2; ++mt)
                acc[mt][nt] = __builtin_amdgcn_mfma_f32_16x16x32_bf16(acur[mt], bfh, acc[mt][nt], 0, 0, 0);
        }
        if (ks < 7) {
            #pragma unroll
            for (int mt = 0; mt < 2; ++mt) acur[mt] = anext[mt];
        }
    }

    // bf16 x gather (5MB table, ~L2/L3 resident)
    uint2 xv[2][4];
    #pragma unroll
    for (int mt = 0; mt < 2; ++mt) {
        const int fc0 = w * 32 + mt * 16 + l4 * 4;
        #pragma unroll
        for (int nt = 0; nt < 4; ++nt)
            xv[mt][nt] = *(const uint2*)(xb + (size_t)colp[nt] * HDIM + fc0);
    }

    f32x4 bc2[2];
    #pragma unroll
    for (int mt = 0; mt < 2; ++mt)
        bc2[mt] = *(const f32x4*)(bf2 + w * 32 + mt * 16 + l4 * 4);

    __syncthreads();   // all hid reads done -> msg overlay

    // msg = (filt+bias)*x -> bf16 LDS, single pass over all 64 rows
    #pragma unroll
    for (int mt = 0; mt < 2; ++mt) {
        const int fc0 = w * 32 + mt * 16 + l4 * 4;
        #pragma unroll
        for (int nt = 0; nt < 4; ++nt) {
            const int row = nt * 16 + l15;
            f32x4 m = (acc[mt][nt] + bc2[mt]) * bf4_to_f32(xv[mt][nt]);
            *(uint2*)(sm + SM_HID + row * 512 +
                      (((fc0 >> 3) ^ (row & 7)) << 4) + (fc0 & 7) * 2) =
                make_uint2(cvt_pk(m[0], m[1]), cvt_pk(m[2], m[3]));
        }
    }
    __syncthreads();

    // segmented reduce: 512 threads = 256 cols x 2 halves of 32 rows.
    // 8-deep batched LDS loads; boundary segment merged via LDS stash.
    {
        const int col = t & 255;
        const int h   = t >> 8;
        const int base = h * 32;
        int* stash_nid   = (int*)(sm + SM_RBF);            // 1 KB (rbf dead)
        float* stash_sum = (float*)(sm + SM_RBF + 1024);   // 1 KB

        float sum = 0.0f;
        int cur = nid_s[base];
        int fnid = 0; float fsum = 0.0f;
        bool held = false;

        #pragma unroll
        for (int c = 0; c < 4; ++c) {
            float v[8];
            #pragma unroll
            for (int i = 0; i < 8; ++i) {
                const int pos = base + c * 8 + i;
                unsigned short u = *(const unsigned short*)(sm + SM_HID + pos * 512 +
                                    (((col >> 3) ^ (pos & 7)) << 4) + (col & 7) * 2);
                union { unsigned int ii; float f; } cv; cv.ii = ((unsigned int)u) << 16;
                v[i] = cv.f;
            }
            #pragma unroll
            for (int i = 0; i < 8; ++i) {
                const int nid = nid_s[base + c * 8 + i];
                if (nid != cur) {
                    if (h == 1 && !held) { fnid = cur; fsum = sum; held = true; }
                    else atomicAdd(&agg[(size_t)cur * HDIM + col], sum);
                    sum = 0.0f; cur = nid;
                }
                sum += v[i];
            }
        }
        if (h == 0) {
            stash_nid[col] = cur; stash_sum[col] = sum;
        } else {
            if (!held) { fnid = cur; fsum = sum; }
            else atomicAdd(&agg[(size_t)cur * HDIM + col], sum);
        }
        __syncthreads();
        if (h == 1) {
            int n0 = stash_nid[col]; float s0 = stash_sum[col];
            if (n0 == fnid) {
                atomicAdd(&agg[(size_t)n0 * HDIM + col], s0 + fsum);
            } else {
                atomicAdd(&agg[(size_t)n0 * HDIM + col], s0);
                atomicAdd(&agg[(size_t)fnid * HDIM + col], fsum);
            }
        }
    }
}

// ---------------------------------------------------------------------------
// Node kernel: 32 rows/block (313 blocks: full CU coverage), 512 threads
// (8 waves, wave owns 32 cols x 2 row-tiles). LDS 16KB. Fused BN partials.
// ---------------------------------------------------------------------------
__global__ __launch_bounds__(512, 4) void node_kernel(
    const float* __restrict__ agg, const float* __restrict__ bu1,
    const float* __restrict__ bu2,
    const unsigned short* __restrict__ Pu1, const unsigned short* __restrict__ Pu2,
    float* __restrict__ hout, float* __restrict__ sums)
{
    __shared__ char sm[16384];    // [32 nodes][256] bf16, XOR-swizzled
    const int t  = threadIdx.x;
    const int r0 = blockIdx.x * RB;
    const int l = t & 63, w = t >> 6;        // 8 waves
    const int l15 = l & 15, l4 = l >> 4;

    // stage agg -> LDS bf16 (16 threads/row, 4 float4 each)
    {
        const int row = t & 31, q = t >> 5;   // q in 0..15
        const bool valid = (r0 + row) < N_NODES;
        const float4* src = (const float4*)(agg + (size_t)(r0 + row) * HDIM) + q * 4;
        #pragma unroll
        for (int i = 0; i < 4; ++i) {
            float4 v = valid ? src[i] : make_float4(0.f, 0.f, 0.f, 0.f);
            const int c0 = q * 16 + i * 4;
            *(uint2*)(sm + row * 512 + (((c0 >> 3) ^ (row & 7)) << 4) + (c0 & 7) * 2) =
                make_uint2(cvt_pk(v.x, v.y), cvt_pk(v.z, v.w));
        }
    }

    short8 acur[2];
    #pragma unroll
    for (int mt = 0; mt < 2; ++mt)
        acur[mt] = *(const short8*)(Pu1 + ((2 * w + mt) * 64 + l) * 8);

    __syncthreads();

    f32x4 acc[2][2];
    #pragma unroll
    for (int mt = 0; mt < 2; ++mt)
        #pragma unroll
        for (int nt = 0; nt < 2; ++nt) acc[mt][nt] = (f32x4)0.0f;

    // GEMM1': midT = Wu1T.aggT
    for (int ks = 0; ks < 8; ++ks) {
        short8 anext[2];
        if (ks < 7) {
            #pragma unroll
            for (int mt = 0; mt < 2; ++mt)
                anext[mt] = *(const short8*)(Pu1 + (((ks + 1) * 16 + 2 * w + mt) * 64 + l) * 8);
        }
        #pragma unroll
        for (int nt = 0; nt < 2; ++nt) {
            const int row = nt * 16 + l15;
            short8 bfa = *(const short8*)(sm + row * 512 +
                            ((((ks << 2) + l4) ^ (row & 7)) << 4));
            #pragma unroll
            for (int mt = 0; mt < 2; ++mt)
                acc[mt][nt] = __builtin_amdgcn_mfma_f32_16x16x32_bf16(acur[mt], bfa, acc[mt][nt], 0, 0, 0);
        }
        if (ks < 7) {
            #pragma unroll
            for (int mt = 0; mt < 2; ++mt) acur[mt] = anext[mt];
        }
    }
    __syncthreads();   // all reads done; overwrite with mid

    #pragma unroll
    for (int mt = 0; mt < 2; ++mt)
        acur[mt] = *(const short8*)(Pu2 + ((2 * w + mt) * 64 + l) * 8);

    // mid = silu(acc + bu1) -> LDS (b64 stores)
    #pragma unroll
    for (int mt = 0; mt < 2; ++mt) {
        const int mc0 = w * 32 + mt * 16 + l4 * 4;
        f32x4 b4 = *(const f32x4*)(bu1 + mc0);
        #pragma unroll
        for (int nt = 0; nt < 2; ++nt) {
            const int row = nt * 16 + l15;
            unsigned int pk0 = cvt_pk(silu_f(acc[mt][nt][0] + b4[0]), silu_f(acc[mt][nt][1] + b4[1]));
            unsigned int pk1 = cvt_pk(silu_f(acc[mt][nt][2] + b4[2]), silu_f(acc[mt][nt][3] + b4[3]));
            *(uint2*)(sm + row * 512 + (((mc0 >> 3) ^ (row & 7)) << 4) + (mc0 & 7) * 2) =
                make_uint2(pk0, pk1);
            acc[mt][nt] = (f32x4)0.0f;
        }
    }
    __syncthreads();

    // GEMM2': hT = Wu2T.midT
    for (int ks = 0; ks < 8; ++ks) {
        short8 anext[2];
        if (ks < 7) {
            #pragma unroll
            for (int mt = 0; mt < 2; ++mt)
                anext[mt] = *(const short8*)(Pu2 + (((ks + 1) * 16 + 2 * w + mt) * 64 + l) * 8);
        }
        #pragma unroll
        for (int nt = 0; nt < 2; ++nt) {
            const int row = nt * 16 + l15;
            short8 bfm = *(const short8*)(sm + row * 512 +
                            ((((ks << 2) + l4) ^ (row & 7)) << 4));
            #pragma unroll
            for (int mt = 0; mt < 2; ++mt)
                acc[mt][nt] = __builtin_amdgcn_mfma_f32_16x16x32_bf16(acur[mt], bfm, acc[mt][nt], 0, 0, 0);
        }
        if (ks < 7) {
            #pragma unroll
            for (int mt = 0; mt < 2; ++mt) acur[mt] = anext[mt];
        }
    }

    // epilogue: float4 h stores + BN partials
    #pragma unroll
    for (int mt = 0; mt < 2; ++mt) {
        const int hc0 = w * 32 + mt * 16 + l4 * 4;
        f32x4 b4 = *(const f32x4*)(bu2 + hc0);
        f32x4 s = (f32x4)0.0f, s2 = (f32x4)0.0f;
        #pragma unroll
        for (int nt = 0; nt < 2; ++nt) {
            const int gr = r0 + nt * 16 + l15;
            if (gr < N_NODES) {
                f32x4 hv = acc[mt][nt] + b4;
                *(f32x4*)(hout + (size_t)gr * HDIM + hc0) = hv;
                s += hv; s2 += hv * hv;
            }
        }
        #pragma unroll
        for (int off = 1; off < 16; off <<= 1) {
            #pragma unroll
            for (int r = 0; r < 4; ++r) {
                s[r]  += __shfl_xor(s[r], off);
                s2[r] += __shfl_xor(s2[r], off);
            }
        }
        if (l15 == 0) {
            #pragma unroll
            for (int r = 0; r < 4; ++r) {
                atomicAdd(&sums[hc0 + r], s[r]);
                atomicAdd(&sums[HDIM + hc0 + r], s2[r]);
            }
        }
    }
}

// ---------------------------------------------------------------------------
__global__ __launch_bounds__(256) void final_kernel(
    const float* __restrict__ x, const float* __restrict__ sums,
    const float* __restrict__ gamma, const float* __restrict__ beta,
    float* __restrict__ out)
{
    const int i4 = blockIdx.x * 256 + threadIdx.x;   // float4 index
    const int j  = (i4 & 63) * 4;
    f32x4 mean = *(const f32x4*)(sums + j) * (1.0f / N_NODES);
    f32x4 s2   = *(const f32x4*)(sums + HDIM + j) * (1.0f / N_NODES);
    f32x4 g    = *(const f32x4*)(gamma + j);
    f32x4 b    = *(const f32x4*)(beta + j);
    f32x4 hv   = ((f32x4*)out)[i4];
    f32x4 xv   = ((const f32x4*)x)[i4];
    f32x4 var  = s2 - mean * mean;
    f32x4 inv;
    #pragma unroll
    for (int r = 0; r < 4; ++r) inv[r] = rsqrtf(var[r] + BN_EPS);
    ((f32x4*)out)[i4] = xv + g * (hv - mean) * inv + b;
}

extern "C" void kernel_launch(void* const* d_in, const int* in_sizes, int n_in,
                              void* d_out, int out_size, void* d_ws, size_t ws_size,
                              hipStream_t stream) {
    const float* x     = (const float*)d_in[0];
    const float* rbf   = (const float*)d_in[1];
    const int*   ei    = (const int*)d_in[2];
    const float* Wf1   = (const float*)d_in[3];
    const float* bf1   = (const float*)d_in[4];
    const float* Wf2   = (const float*)d_in[5];
    const float* bf2   = (const float*)d_in[6];
    const float* Wu1   = (const float*)d_in[7];
    const float* bu1   = (const float*)d_in[8];
    const float* Wu2   = (const float*)d_in[9];
    const float* bu2   = (const float*)d_in[10];
    const float* gamma = (const float*)d_in[11];
    const float* beta  = (const float*)d_in[12];
    float* out = (float*)d_out;

    char* ws = (char*)d_ws;
    float* agg     = (float*)(ws);                            // 10,240,000 B
    float* sums    = (float*)(ws + 10240000);                 // 2,048 B
    int*   cnt     = (int*)(ws + 10242048);                   // 40,960 B
    int*   nodepos = (int*)(ws + 10283008);                   // 1,280,000 B
    unsigned short* Pf2 = (unsigned short*)(ws + 11563008);   // 131,072 B
    unsigned short* Pu1 = (unsigned short*)(ws + 11694080);   // 131,072 B
    unsigned short* Pu2 = (unsigned short*)(ws + 11825152);   // 131,072 B
    unsigned short* P1  = (unsigned short*)(ws + 11956224);   // 16,384 B

    // d_out scratch (fully overwritten by node_kernel afterwards):
    //   [0, 5.12MB): bf16 x    [5.12MB, 7.68MB): packed {edge, col} int2
    unsigned short* xb = (unsigned short*)d_out;
    int2* pc = (int2*)((char*)d_out + 5120000);

    // one memset covers agg + sums + cnt (contiguous)
    hipMemsetAsync(agg, 0, 10283008, stream);

    prep_hist_kernel<<<3300, 256, 0, stream>>>(Wf2, Wu1, Wu2, Wf1, bf1, ei, x,
                                               Pf2, Pu1, Pu2, P1, cnt, xb);
    scan_kernel<<<1, 256, 0, stream>>>(cnt);
    fill_kernel<<<E_EDGES / 256, 256, 0, stream>>>(ei, ei + E_EDGES, cnt,
                                                   pc, nodepos);

    edge_kernel<<<E_EDGES / 64, 512, 0, stream>>>(
        rbf, pc, nodepos, P1, Pf2, bf2, xb, agg);
    node_kernel<<<(N_NODES + RB - 1) / RB, 512, 0, stream>>>(
        agg, bu1, bu2, Pu1, Pu2, out, sums);
    final_kernel<<<(N_NODES * HDIM / 4) / 256, 256, 0, stream>>>(
        x, sums, gamma, beta, out);
}

// Round 14
// 189.736 us; speedup vs baseline: 1.0791x; 1.0308x over previous
//
#include <hip/hip_runtime.h>

#define N_NODES 10000
#define E_EDGES 320000
#define HDIM    256
#define NG      20
#define BN_EPS  1e-5f

typedef __attribute__((ext_vector_type(8))) short short8;
typedef __attribute__((ext_vector_type(4))) float f32x4;

__device__ __forceinline__ float silu_f(float v) {
    float e = __expf(-v);
    return v * __builtin_amdgcn_rcpf(1.0f + e);
}

__device__ __forceinline__ unsigned int cvt_pk(float lo, float hi) {
    unsigned int r;
    asm("v_cvt_pk_bf16_f32 %0, %1, %2" : "=v"(r) : "v"(lo), "v"(hi));
    return r;
}

__device__ __forceinline__ unsigned short f2bf(float f) {
    union { float f; unsigned int u; } v; v.f = f;
    unsigned int r = v.u + 0x7fffu + ((v.u >> 16) & 1u);   // RNE
    return (unsigned short)(r >> 16);
}

__device__ __forceinline__ f32x4 bf4_to_f32(uint2 u) {
    union { unsigned int i; float f; } a, b, c, d;
    a.i = u.x << 16; b.i = u.x & 0xFFFF0000u;
    c.i = u.y << 16; d.i = u.y & 0xFFFF0000u;
    return (f32x4){a.f, b.f, c.f, d.f};
}

// ---------------------------------------------------------------------------
// Fused prep: weight packing + edge histogram + x -> bf16 cast.
// ---------------------------------------------------------------------------
__global__ __launch_bounds__(256) void prep_hist_kernel(
    const float* __restrict__ Wf2, const float* __restrict__ Wu1,
    const float* __restrict__ Wu2, const float* __restrict__ Wf1,
    const float* __restrict__ bf1, const int* __restrict__ ei_row,
    const float* __restrict__ x,
    unsigned short* __restrict__ Pf2, unsigned short* __restrict__ Pu1,
    unsigned short* __restrict__ Pu2, unsigned short* __restrict__ P1,
    int* __restrict__ cnt, unsigned short* __restrict__ xb)
{
    const int bx = blockIdx.x;
    if (bx >= 2050) {
        const int idx = ((bx - 2050) * 256 + threadIdx.x) * 8;
        const float4* s = (const float4*)(x + idx);
        float4 a = s[0], b = s[1];
        *(uint4*)(xb + idx) = make_uint4(cvt_pk(a.x, a.y), cvt_pk(a.z, a.w),
                                         cvt_pk(b.x, b.y), cvt_pk(b.z, b.w));
        return;
    }
    if (bx >= 800) {
        int e = (bx - 800) * 256 + threadIdx.x;
        atomicAdd(&cnt[ei_row[e]], 1);
        return;
    }
    int tid = bx * 256 + threadIdx.x;
    if (tid < 196608) {
        int which = tid >> 16, local = tid & 65535;
        const float* W = (which == 0) ? Wf2 : (which == 1) ? Wu1 : Wu2;
        unsigned short* P = (which == 0) ? Pf2 : (which == 1) ? Pu1 : Pu2;
        int j = local & 7, lane = (local >> 3) & 63;
        int ntile = (local >> 9) & 15, kstep = local >> 13;
        int k = kstep * 32 + (lane >> 4) * 8 + j;
        int n = ntile * 16 + (lane & 15);
        P[local] = f2bf(W[k * 256 + n]);
    } else {
        int local = tid - 196608;   // 0..8191
        int j = local & 7, lane = (local >> 3) & 63, ntile = local >> 9;
        int k = (lane >> 4) * 8 + j;
        int n = ntile * 16 + (lane & 15);
        float v = (k < NG) ? Wf1[k * 256 + n] : (k == NG ? bf1[n] : 0.0f);
        P1[local] = f2bf(v);
    }
}

// ---------------------------------------------------------------------------
// CSR build: scan + fill (fill packs edge id + col into one int2 store)
// ---------------------------------------------------------------------------
__global__ __launch_bounds__(256) void scan_kernel(int* __restrict__ cnt) {
    __shared__ int tot[256];
    const int t = threadIdx.x;
    int loc[40];
    int s = 0;
    #pragma unroll
    for (int i = 0; i < 40; ++i) { loc[i] = cnt[t * 40 + i]; s += loc[i]; }
    tot[t] = s;
    __syncthreads();
    for (int off = 1; off < 256; off <<= 1) {
        int u = (t >= off) ? tot[t - off] : 0;
        __syncthreads();
        tot[t] += u;
        __syncthreads();
    }
    int pre = tot[t] - s;
    #pragma unroll
    for (int i = 0; i < 40; ++i) { int v = loc[i]; cnt[t * 40 + i] = pre; pre += v; }
}

__global__ __launch_bounds__(256) void fill_kernel(const int* __restrict__ ei_row,
                                                   const int* __restrict__ ei_col,
                                                   int* __restrict__ cnt,
                                                   int2* __restrict__ pc,
                                                   int* __restrict__ nodepos) {
    int e = blockIdx.x * 256 + threadIdx.x;
    int r = ei_row[e];
    int c = ei_col[e];
    int pos = atomicAdd(&cnt[r], 1);
    pc[pos] = make_int2(e, c);
    nodepos[pos] = r;
}

// ---------------------------------------------------------------------------
// Edge kernel: 64 CSR-ordered edges / block, 8 waves (512 thr), 3 blocks/CU.
// GEMM1 (swapped): hiddenT = Wf1T.rbfT; rbf staged once in LDS (80B rows).
// GEMM2 (swapped): filtT = Wf2T.hiddenT; A-frags streamed from L2 packed W
//   with a 3-deep software pipeline (1-deep left ~160cyc/ks exposed).
// msg = (filt+bf2)*xb[col] stored bf16 (single pass, all 64 rows).
// Reduce: 512 threads = 256 cols x 2 halves of 32 rows; 8-deep batched LDS
// loads; boundary merged via LDS stash; contiguous per-node-row atomics.
// ---------------------------------------------------------------------------
#define SM_NID 0        // 64 int (256 B)
#define SM_RBF 256      // [64][40] ushort rows of 80 B (5120 B); stash overlay
#define SM_HID 5376     // 32768 B: hid bf16 [64][256] swz / msg bf16 overlay
#define SM_TOT 38144

__global__ __launch_bounds__(512, 6) void edge_kernel(
    const float* __restrict__ rbf, const int2* __restrict__ pc,
    const int* __restrict__ nodepos,
    const unsigned short* __restrict__ P1, const unsigned short* __restrict__ P2,
    const float* __restrict__ bf2, const unsigned short* __restrict__ xb,
    float* __restrict__ agg)
{
    __shared__ char sm[SM_TOT];
    int* nid_s = (int*)(sm + SM_NID);

    const int t = threadIdx.x;
    int blk = blockIdx.x;
    blk = (blk & 7) * 625 + (blk >> 3);   // XCD swizzle (5000 = 8*625, bijective)
    const int p0 = blk * 64;
    const int l = t & 63, w = t >> 6;
    const int l15 = l & 15, l4 = l >> 4;

    if (t < 64) nid_s[t] = nodepos[p0 + t];
    // rbf -> LDS bf16, 80 B rows; k=20 bias row (1.0), 21..31 zero
    if (t < 128) {
        const int row = t >> 1, half = t & 1;
        const float* rp = rbf + (size_t)pc[p0 + row].x * NG + half * 10;
        float v[10];
        if (half == 0) {
            float4 a = *(const float4*)rp, b = *(const float4*)(rp + 4);
            float2 c = *(const float2*)(rp + 8);
            v[0]=a.x; v[1]=a.y; v[2]=a.z; v[3]=a.w; v[4]=b.x;
            v[5]=b.y; v[6]=b.z; v[7]=b.w; v[8]=c.x; v[9]=c.y;
        } else {
            float2 a = *(const float2*)rp;
            float4 b = *(const float4*)(rp + 2), c = *(const float4*)(rp + 6);
            v[0]=a.x; v[1]=a.y; v[2]=b.x; v[3]=b.y; v[4]=b.z;
            v[5]=b.w; v[6]=c.x; v[7]=c.y; v[8]=c.z; v[9]=c.w;
        }
        unsigned int* dst = (unsigned int*)(sm + SM_RBF + row * 80 + half * 20);
        #pragma unroll
        for (int i = 0; i < 5; ++i) dst[i] = cvt_pk(v[2*i], v[2*i+1]);
    } else if (t < 192) {
        const int row = t - 128;
        *(unsigned long long*)(sm + SM_RBF + row * 80 + 40) = 0x3F80ull; // 1.0,0,0,0
        *(uint4*)(sm + SM_RBF + row * 80 + 48) = make_uint4(0, 0, 0, 0);
    }

    // per-thread edge columns (packed with edge id, no dependent gather)
    int colp[4];
    #pragma unroll
    for (int nt = 0; nt < 4; ++nt) colp[nt] = pc[p0 + nt * 16 + l15].y;

    // GEMM1 A-frags (Wf1T); GEMM2 3-deep A-frag pipeline slots ks=0,1,2
    short8 a1[2], abuf[3][2];
    #pragma unroll
    for (int mt = 0; mt < 2; ++mt)
        a1[mt] = *(const short8*)(P1 + ((2 * w + mt) * 64 + l) * 8);
    #pragma unroll
    for (int p = 0; p < 3; ++p)
        #pragma unroll
        for (int mt = 0; mt < 2; ++mt)
            abuf[p][mt] = *(const short8*)(P2 + ((p * 16 + 2 * w + mt) * 64 + l) * 8);

    __syncthreads();

    f32x4 acc[2][4];   // [mt][nt]
    #pragma unroll
    for (int mt = 0; mt < 2; ++mt)
        #pragma unroll
        for (int nt = 0; nt < 4; ++nt) acc[mt][nt] = (f32x4)0.0f;

    // GEMM1: one K=32 step; B = rbfT from LDS (stride 80B)
    #pragma unroll
    for (int nt = 0; nt < 4; ++nt) {
        short8 bfr = *(const short8*)(sm + SM_RBF + (nt * 16 + l15) * 80 + l4 * 16);
        #pragma unroll
        for (int mt = 0; mt < 2; ++mt)
            acc[mt][nt] = __builtin_amdgcn_mfma_f32_16x16x32_bf16(a1[mt], bfr, acc[mt][nt], 0, 0, 0);
    }

    // silu -> hid bf16, XOR-swizzled, b64 stores
    #pragma unroll
    for (int mt = 0; mt < 2; ++mt) {
        const int hc0 = w * 32 + mt * 16 + l4 * 4;
        #pragma unroll
        for (int nt = 0; nt < 4; ++nt) {
            const int row = nt * 16 + l15;
            unsigned int pk0 = cvt_pk(silu_f(acc[mt][nt][0]), silu_f(acc[mt][nt][1]));
            unsigned int pk1 = cvt_pk(silu_f(acc[mt][nt][2]), silu_f(acc[mt][nt][3]));
            *(uint2*)(sm + SM_HID + row * 512 +
                      (((hc0 >> 3) ^ (row & 7)) << 4) + (hc0 & 7) * 2) =
                make_uint2(pk0, pk1);
        }
    }
    __syncthreads();

    // GEMM2: filtT = Wf2T.hiddenT; 3-deep pipelined A-frag stream
    #pragma unroll
    for (int mt = 0; mt < 2; ++mt)
        #pragma unroll
        for (int nt = 0; nt < 4; ++nt) acc[mt][nt] = (f32x4)0.0f;

    #pragma unroll
    for (int ks = 0; ks < 8; ++ks) {
        const int slot = ks % 3;
        short8 acur0 = abuf[slot][0];
        short8 acur1 = abuf[slot][1];
        if (ks < 5) {
            #pragma unroll
            for (int mt = 0; mt < 2; ++mt)
                abuf[slot][mt] = *(const short8*)(P2 + (((ks + 3) * 16 + 2 * w + mt) * 64 + l) * 8);
        }
        #pragma unroll
        for (int nt = 0; nt < 4; ++nt) {
            const int row = nt * 16 + l15;
            short8 bfh = *(const short8*)(sm + SM_HID + row * 512 +
                            ((((ks << 2) + l4) ^ (row & 7)) << 4));
            acc[0][nt] = __builtin_amdgcn_mfma_f32_16x16x32_bf16(acur0, bfh, acc[0][nt], 0, 0, 0);
            acc[1][nt] = __builtin_amdgcn_mfma_f32_16x16x32_bf16(acur1, bfh, acc[1][nt], 0, 0, 0);
        }
    }

    // bf16 x gather (5MB table, ~L2/L3 resident)
    uint2 xv[2][4];
    #pragma unroll
    for (int mt = 0; mt < 2; ++mt) {
        const int fc0 = w * 32 + mt * 16 + l4 * 4;
        #pragma unroll
        for (int nt = 0; nt < 4; ++nt)
            xv[mt][nt] = *(const uint2*)(xb + (size_t)colp[nt] * HDIM + fc0);
    }

    f32x4 bc2[2];
    #pragma unroll
    for (int mt = 0; mt < 2; ++mt)
        bc2[mt] = *(const f32x4*)(bf2 + w * 32 + mt * 16 + l4 * 4);

    __syncthreads();   // all hid reads done -> msg overlay

    // msg = (filt+bias)*x -> bf16 LDS, single pass over all 64 rows
    #pragma unroll
    for (int mt = 0; mt < 2; ++mt) {
        const int fc0 = w * 32 + mt * 16 + l4 * 4;
        #pragma unroll
        for (int nt = 0; nt < 4; ++nt) {
            const int row = nt * 16 + l15;
            f32x4 m = (acc[mt][nt] + bc2[mt]) * bf4_to_f32(xv[mt][nt]);
            *(uint2*)(sm + SM_HID + row * 512 +
                      (((fc0 >> 3) ^ (row & 7)) << 4) + (fc0 & 7) * 2) =
                make_uint2(cvt_pk(m[0], m[1]), cvt_pk(m[2], m[3]));
        }
    }
    __syncthreads();

    // segmented reduce: 512 threads = 256 cols x 2 halves of 32 rows.
    // 8-deep batched LDS loads; boundary segment merged via LDS stash.
    {
        const int col = t & 255;
        const int h   = t >> 8;
        const int base = h * 32;
        int* stash_nid   = (int*)(sm + SM_RBF);            // 1 KB (rbf dead)
        float* stash_sum = (float*)(sm + SM_RBF + 1024);   // 1 KB

        float sum = 0.0f;
        int cur = nid_s[base];
        int fnid = 0; float fsum = 0.0f;
        bool held = false;

        #pragma unroll
        for (int c = 0; c < 4; ++c) {
            float v[8];
            #pragma unroll
            for (int i = 0; i < 8; ++i) {
                const int pos = base + c * 8 + i;
                unsigned short u = *(const unsigned short*)(sm + SM_HID + pos * 512 +
                                    (((col >> 3) ^ (pos & 7)) << 4) + (col & 7) * 2);
                union { unsigned int ii; float f; } cv; cv.ii = ((unsigned int)u) << 16;
                v[i] = cv.f;
            }
            #pragma unroll
            for (int i = 0; i < 8; ++i) {
                const int nid = nid_s[base + c * 8 + i];
                if (nid != cur) {
                    if (h == 1 && !held) { fnid = cur; fsum = sum; held = true; }
                    else atomicAdd(&agg[(size_t)cur * HDIM + col], sum);
                    sum = 0.0f; cur = nid;
                }
                sum += v[i];
            }
        }
        if (h == 0) {
            stash_nid[col] = cur; stash_sum[col] = sum;
        } else {
            if (!held) { fnid = cur; fsum = sum; }
            else atomicAdd(&agg[(size_t)cur * HDIM + col], sum);
        }
        __syncthreads();
        if (h == 1) {
            int n0 = stash_nid[col]; float s0 = stash_sum[col];
            if (n0 == fnid) {
                atomicAdd(&agg[(size_t)n0 * HDIM + col], s0 + fsum);
            } else {
                atomicAdd(&agg[(size_t)n0 * HDIM + col], s0);
                atomicAdd(&agg[(size_t)fnid * HDIM + col], fsum);
            }
        }
    }
}

// ---------------------------------------------------------------------------
// Node kernel: 64 rows/block, 512 threads (8 waves, wave owns 32 cols),
// both GEMMs swapped, fused BN partials. LDS 32KB. (r11 configuration.)
// ---------------------------------------------------------------------------
__global__ __launch_bounds__(512, 2) void node_kernel(
    const float* __restrict__ agg, const float* __restrict__ bu1,
    const float* __restrict__ bu2,
    const unsigned short* __restrict__ Pu1, const unsigned short* __restrict__ Pu2,
    float* __restrict__ hout, float* __restrict__ sums)
{
    __shared__ char sm[32768];    // [64 nodes][256] bf16, XOR-swizzled
    const int t  = threadIdx.x;
    const int r0 = blockIdx.x * 64;
    const int l = t & 63, w = t >> 6;        // 8 waves
    const int l15 = l & 15, l4 = l >> 4;

    // stage agg -> LDS bf16 (8 threads/row, 8 float4 each)
    {
        const int row = t & 63, q = t >> 6;
        const bool valid = (r0 + row) < N_NODES;
        const float4* src = (const float4*)(agg + (size_t)(r0 + row) * HDIM) + q * 8;
        #pragma unroll
        for (int i = 0; i < 8; ++i) {
            float4 v = valid ? src[i] : make_float4(0.f, 0.f, 0.f, 0.f);
            const int c0 = q * 32 + i * 4;
            *(uint2*)(sm + row * 512 + (((c0 >> 3) ^ (row & 7)) << 4) + (c0 & 7) * 2) =
                make_uint2(cvt_pk(v.x, v.y), cvt_pk(v.z, v.w));
        }
    }

    short8 acur[2];
    #pragma unroll
    for (int mt = 0; mt < 2; ++mt)
        acur[mt] = *(const short8*)(Pu1 + ((2 * w + mt) * 64 + l) * 8);

    __syncthreads();

    f32x4 acc[2][4];
    #pragma unroll
    for (int mt = 0; mt < 2; ++mt)
        #pragma unroll
        for (int nt = 0; nt < 4; ++nt) acc[mt][nt] = (f32x4)0.0f;

    // GEMM1': midT = Wu1T.aggT
    for (int ks = 0; ks < 8; ++ks) {
        short8 anext[2];
        if (ks < 7) {
            #pragma unroll
            for (int mt = 0; mt < 2; ++mt)
                anext[mt] = *(const short8*)(Pu1 + (((ks + 1) * 16 + 2 * w + mt) * 64 + l) * 8);
        }
        #pragma unroll
        for (int nt = 0; nt < 4; ++nt) {
            const int row = nt * 16 + l15;
            short8 bfa = *(const short8*)(sm + row * 512 +
                            ((((ks << 2) + l4) ^ (row & 7)) << 4));
            #pragma unroll
            for (int mt = 0; mt < 2; ++mt)
                acc[mt][nt] = __builtin_amdgcn_mfma_f32_16x16x32_bf16(acur[mt], bfa, acc[mt][nt], 0, 0, 0);
        }
        if (ks < 7) {
            #pragma unroll
            for (int mt = 0; mt < 2; ++mt) acur[mt] = anext[mt];
        }
    }
    __syncthreads();   // all reads done; overwrite with mid

    #pragma unroll
    for (int mt = 0; mt < 2; ++mt)
        acur[mt] = *(const short8*)(Pu2 + ((2 * w + mt) * 64 + l) * 8);

    // mid = silu(acc + bu1) -> LDS (b64 stores)
    #pragma unroll
    for (int mt = 0; mt < 2; ++mt) {
        const int mc0 = w * 32 + mt * 16 + l4 * 4;
        f32x4 b4 = *(const f32x4*)(bu1 + mc0);
        #pragma unroll
        for (int nt = 0; nt < 4; ++nt) {
            const int row = nt * 16 + l15;
            unsigned int pk0 = cvt_pk(silu_f(acc[mt][nt][0] + b4[0]), silu_f(acc[mt][nt][1] + b4[1]));
            unsigned int pk1 = cvt_pk(silu_f(acc[mt][nt][2] + b4[2]), silu_f(acc[mt][nt][3] + b4[3]));
            *(uint2*)(sm + row * 512 + (((mc0 >> 3) ^ (row & 7)) << 4) + (mc0 & 7) * 2) =
                make_uint2(pk0, pk1);
            acc[mt][nt] = (f32x4)0.0f;
        }
    }
    __syncthreads();

    // GEMM2': hT = Wu2T.midT
    for (int ks = 0; ks < 8; ++ks) {
        short8 anext[2];
        if (ks < 7) {
            #pragma unroll
            for (int mt = 0; mt < 2; ++mt)
                anext[mt] = *(const short8*)(Pu2 + (((ks + 1) * 16 + 2 * w + mt) * 64 + l) * 8);
        }
        #pragma unroll
        for (int nt = 0; nt < 4; ++nt) {
            const int row = nt * 16 + l15;
            short8 bfm = *(const short8*)(sm + row * 512 +
                            ((((ks << 2) + l4) ^ (row & 7)) << 4));
            #pragma unroll
            for (int mt = 0; mt < 2; ++mt)
                acc[mt][nt] = __builtin_amdgcn_mfma_f32_16x16x32_bf16(acur[mt], bfm, acc[mt][nt], 0, 0, 0);
        }
        if (ks < 7) {
            #pragma unroll
            for (int mt = 0; mt < 2; ++mt) acur[mt] = anext[mt];
        }
    }

    // epilogue: float4 h stores + BN partials
    #pragma unroll
    for (int mt = 0; mt < 2; ++mt) {
        const int hc0 = w * 32 + mt * 16 + l4 * 4;
        f32x4 b4 = *(const f32x4*)(bu2 + hc0);
        f32x4 s = (f32x4)0.0f, s2 = (f32x4)0.0f;
        #pragma unroll
        for (int nt = 0; nt < 4; ++nt) {
            const int gr = r0 + nt * 16 + l15;
            if (gr < N_NODES) {
                f32x4 hv = acc[mt][nt] + b4;
                *(f32x4*)(hout + (size_t)gr * HDIM + hc0) = hv;
                s += hv; s2 += hv * hv;
            }
        }
        #pragma unroll
        for (int off = 1; off < 16; off <<= 1) {
            #pragma unroll
            for (int r = 0; r < 4; ++r) {
                s[r]  += __shfl_xor(s[r], off);
                s2[r] += __shfl_xor(s2[r], off);
            }
        }
        if (l15 == 0) {
            #pragma unroll
            for (int r = 0; r < 4; ++r) {
                atomicAdd(&sums[hc0 + r], s[r]);
                atomicAdd(&sums[HDIM + hc0 + r], s2[r]);
            }
        }
    }
}

// ---------------------------------------------------------------------------
__global__ __launch_bounds__(256) void final_kernel(
    const float* __restrict__ x, const float* __restrict__ sums,
    const float* __restrict__ gamma, const float* __restrict__ beta,
    float* __restrict__ out)
{
    const int i4 = blockIdx.x * 256 + threadIdx.x;   // float4 index
    const int j  = (i4 & 63) * 4;
    f32x4 mean = *(const f32x4*)(sums + j) * (1.0f / N_NODES);
    f32x4 s2   = *(const f32x4*)(sums + HDIM + j) * (1.0f / N_NODES);
    f32x4 g    = *(const f32x4*)(gamma + j);
    f32x4 b    = *(const f32x4*)(beta + j);
    f32x4 hv   = ((f32x4*)out)[i4];
    f32x4 xv   = ((const f32x4*)x)[i4];
    f32x4 var  = s2 - mean * mean;
    f32x4 inv;
    #pragma unroll
    for (int r = 0; r < 4; ++r) inv[r] = rsqrtf(var[r] + BN_EPS);
    ((f32x4*)out)[i4] = xv + g * (hv - mean) * inv + b;
}

extern "C" void kernel_launch(void* const* d_in, const int* in_sizes, int n_in,
                              void* d_out, int out_size, void* d_ws, size_t ws_size,
                              hipStream_t stream) {
    const float* x     = (const float*)d_in[0];
    const float* rbf   = (const float*)d_in[1];
    const int*   ei    = (const int*)d_in[2];
    const float* Wf1   = (const float*)d_in[3];
    const float* bf1   = (const float*)d_in[4];
    const float* Wf2   = (const float*)d_in[5];
    const float* bf2   = (const float*)d_in[6];
    const float* Wu1   = (const float*)d_in[7];
    const float* bu1   = (const float*)d_in[8];
    const float* Wu2   = (const float*)d_in[9];
    const float* bu2   = (const float*)d_in[10];
    const float* gamma = (const float*)d_in[11];
    const float* beta  = (const float*)d_in[12];
    float* out = (float*)d_out;

    char* ws = (char*)d_ws;
    float* agg     = (float*)(ws);                            // 10,240,000 B
    float* sums    = (float*)(ws + 10240000);                 // 2,048 B
    int*   cnt     = (int*)(ws + 10242048);                   // 40,960 B
    int*   nodepos = (int*)(ws + 10283008);                   // 1,280,000 B
    unsigned short* Pf2 = (unsigned short*)(ws + 11563008);   // 131,072 B
    unsigned short* Pu1 = (unsigned short*)(ws + 11694080);   // 131,072 B
    unsigned short* Pu2 = (unsigned short*)(ws + 11825152);   // 131,072 B
    unsigned short* P1  = (unsigned short*)(ws + 11956224);   // 16,384 B

    // d_out scratch (fully overwritten by node_kernel afterwards):
    //   [0, 5.12MB): bf16 x    [5.12MB, 7.68MB): packed {edge, col} int2
    unsigned short* xb = (unsigned short*)d_out;
    int2* pc = (int2*)((char*)d_out + 5120000);

    // one memset covers agg + sums + cnt (contiguous)
    hipMemsetAsync(agg, 0, 10283008, stream);

    prep_hist_kernel<<<3300, 256, 0, stream>>>(Wf2, Wu1, Wu2, Wf1, bf1, ei, x,
                                               Pf2, Pu1, Pu2, P1, cnt, xb);
    scan_kernel<<<1, 256, 0, stream>>>(cnt);
    fill_kernel<<<E_EDGES / 256, 256, 0, stream>>>(ei, ei + E_EDGES, cnt,
                                                   pc, nodepos);

    edge_kernel<<<E_EDGES / 64, 512, 0, stream>>>(
        rbf, pc, nodepos, P1, Pf2, bf2, xb, agg);
    node_kernel<<<(N_NODES + 63) / 64, 512, 0, stream>>>(
        agg, bu1, bu2, Pu1, Pu2, out, sums);
    final_kernel<<<(N_NODES * HDIM / 4) / 256, 256, 0, stream>>>(
        x, sums, gamma, beta, out);
}

// Round 15
// 182.563 us; speedup vs baseline: 1.1215x; 1.0393x over previous
//
#include <hip/hip_runtime.h>

#define N_NODES 10000
#define E_EDGES 320000
#define HDIM    256
#define NG      20
#define BN_EPS  1e-5f

typedef __attribute__((ext_vector_type(8))) short short8;
typedef __attribute__((ext_vector_type(4))) float f32x4;

__device__ __forceinline__ float silu_f(float v) {
    float e = __expf(-v);
    return v * __builtin_amdgcn_rcpf(1.0f + e);
}

__device__ __forceinline__ unsigned int cvt_pk(float lo, float hi) {
    unsigned int r;
    asm("v_cvt_pk_bf16_f32 %0, %1, %2" : "=v"(r) : "v"(lo), "v"(hi));
    return r;
}

__device__ __forceinline__ unsigned short f2bf(float f) {
    union { float f; unsigned int u; } v; v.f = f;
    unsigned int r = v.u + 0x7fffu + ((v.u >> 16) & 1u);   // RNE
    return (unsigned short)(r >> 16);
}

__device__ __forceinline__ f32x4 bf4_to_f32(uint2 u) {
    union { unsigned int i; float f; } a, b, c, d;
    a.i = u.x << 16; b.i = u.x & 0xFFFF0000u;
    c.i = u.y << 16; d.i = u.y & 0xFFFF0000u;
    return (f32x4){a.f, b.f, c.f, d.f};
}

// ---------------------------------------------------------------------------
// Fused prep: weight packing + edge histogram + x -> bf16 cast.
// ---------------------------------------------------------------------------
__global__ __launch_bounds__(256) void prep_hist_kernel(
    const float* __restrict__ Wf2, const float* __restrict__ Wu1,
    const float* __restrict__ Wu2, const float* __restrict__ Wf1,
    const float* __restrict__ bf1, const int* __restrict__ ei_row,
    const float* __restrict__ x,
    unsigned short* __restrict__ Pf2, unsigned short* __restrict__ Pu1,
    unsigned short* __restrict__ Pu2, unsigned short* __restrict__ P1,
    int* __restrict__ cnt, unsigned short* __restrict__ xb)
{
    const int bx = blockIdx.x;
    if (bx >= 2050) {
        const int idx = ((bx - 2050) * 256 + threadIdx.x) * 8;
        const float4* s = (const float4*)(x + idx);
        float4 a = s[0], b = s[1];
        *(uint4*)(xb + idx) = make_uint4(cvt_pk(a.x, a.y), cvt_pk(a.z, a.w),
                                         cvt_pk(b.x, b.y), cvt_pk(b.z, b.w));
        return;
    }
    if (bx >= 800) {
        int e = (bx - 800) * 256 + threadIdx.x;
        atomicAdd(&cnt[ei_row[e]], 1);
        return;
    }
    int tid = bx * 256 + threadIdx.x;
    if (tid < 196608) {
        int which = tid >> 16, local = tid & 65535;
        const float* W = (which == 0) ? Wf2 : (which == 1) ? Wu1 : Wu2;
        unsigned short* P = (which == 0) ? Pf2 : (which == 1) ? Pu1 : Pu2;
        int j = local & 7, lane = (local >> 3) & 63;
        int ntile = (local >> 9) & 15, kstep = local >> 13;
        int k = kstep * 32 + (lane >> 4) * 8 + j;
        int n = ntile * 16 + (lane & 15);
        P[local] = f2bf(W[k * 256 + n]);
    } else {
        int local = tid - 196608;   // 0..8191
        int j = local & 7, lane = (local >> 3) & 63, ntile = local >> 9;
        int k = (lane >> 4) * 8 + j;
        int n = ntile * 16 + (lane & 15);
        float v = (k < NG) ? Wf1[k * 256 + n] : (k == NG ? bf1[n] : 0.0f);
        P1[local] = f2bf(v);
    }
}

// ---------------------------------------------------------------------------
// CSR build: scan + fill (fill packs edge id + col into one int2 store)
// ---------------------------------------------------------------------------
__global__ __launch_bounds__(256) void scan_kernel(int* __restrict__ cnt) {
    __shared__ int tot[256];
    const int t = threadIdx.x;
    int loc[40];
    int s = 0;
    #pragma unroll
    for (int i = 0; i < 40; ++i) { loc[i] = cnt[t * 40 + i]; s += loc[i]; }
    tot[t] = s;
    __syncthreads();
    for (int off = 1; off < 256; off <<= 1) {
        int u = (t >= off) ? tot[t - off] : 0;
        __syncthreads();
        tot[t] += u;
        __syncthreads();
    }
    int pre = tot[t] - s;
    #pragma unroll
    for (int i = 0; i < 40; ++i) { int v = loc[i]; cnt[t * 40 + i] = pre; pre += v; }
}

__global__ __launch_bounds__(256) void fill_kernel(const int* __restrict__ ei_row,
                                                   const int* __restrict__ ei_col,
                                                   int* __restrict__ cnt,
                                                   int2* __restrict__ pc,
                                                   int* __restrict__ nodepos) {
    int e = blockIdx.x * 256 + threadIdx.x;
    int r = ei_row[e];
    int c = ei_col[e];
    int pos = atomicAdd(&cnt[r], 1);
    pc[pos] = make_int2(e, c);
    nodepos[pos] = r;
}

// ---------------------------------------------------------------------------
// Edge kernel (r13 configuration — best measured: 98.4 us steady-state):
// 64 CSR-ordered edges / block, 8 waves (512 thr), 3 blocks/CU.
// GEMM1 (swapped): hiddenT = Wf1T.rbfT; rbf staged once in LDS (80B rows).
// GEMM2 (swapped): filtT = Wf2T.hiddenT; A-frags streamed from L2 packed W
//   with 1-deep prefetch (3-deep regressed in r14: slot rotation overhead).
// msg = (filt+bf2)*xb[col] stored bf16 (single pass, all 64 rows).
// Reduce: 512 threads = 256 cols x 2 halves of 32 rows; 8-deep batched LDS
// loads; boundary merged via LDS stash; contiguous per-node-row atomics.
// ---------------------------------------------------------------------------
#define SM_NID 0        // 64 int (256 B)
#define SM_RBF 256      // [64][40] ushort rows of 80 B (5120 B); stash overlay
#define SM_HID 5376     // 32768 B: hid bf16 [64][256] swz / msg bf16 overlay
#define SM_TOT 38144

__global__ __launch_bounds__(512, 6) void edge_kernel(
    const float* __restrict__ rbf, const int2* __restrict__ pc,
    const int* __restrict__ nodepos,
    const unsigned short* __restrict__ P1, const unsigned short* __restrict__ P2,
    const float* __restrict__ bf2, const unsigned short* __restrict__ xb,
    float* __restrict__ agg)
{
    __shared__ char sm[SM_TOT];
    int* nid_s = (int*)(sm + SM_NID);

    const int t = threadIdx.x;
    int blk = blockIdx.x;
    blk = (blk & 7) * 625 + (blk >> 3);   // XCD swizzle (5000 = 8*625, bijective)
    const int p0 = blk * 64;
    const int l = t & 63, w = t >> 6;
    const int l15 = l & 15, l4 = l >> 4;

    if (t < 64) nid_s[t] = nodepos[p0 + t];
    // rbf -> LDS bf16, 80 B rows; k=20 bias row (1.0), 21..31 zero
    if (t < 128) {
        const int row = t >> 1, half = t & 1;
        const float* rp = rbf + (size_t)pc[p0 + row].x * NG + half * 10;
        float v[10];
        if (half == 0) {
            float4 a = *(const float4*)rp, b = *(const float4*)(rp + 4);
            float2 c = *(const float2*)(rp + 8);
            v[0]=a.x; v[1]=a.y; v[2]=a.z; v[3]=a.w; v[4]=b.x;
            v[5]=b.y; v[6]=b.z; v[7]=b.w; v[8]=c.x; v[9]=c.y;
        } else {
            float2 a = *(const float2*)rp;
            float4 b = *(const float4*)(rp + 2), c = *(const float4*)(rp + 6);
            v[0]=a.x; v[1]=a.y; v[2]=b.x; v[3]=b.y; v[4]=b.z;
            v[5]=b.w; v[6]=c.x; v[7]=c.y; v[8]=c.z; v[9]=c.w;
        }
        unsigned int* dst = (unsigned int*)(sm + SM_RBF + row * 80 + half * 20);
        #pragma unroll
        for (int i = 0; i < 5; ++i) dst[i] = cvt_pk(v[2*i], v[2*i+1]);
    } else if (t < 192) {
        const int row = t - 128;
        *(unsigned long long*)(sm + SM_RBF + row * 80 + 40) = 0x3F80ull; // 1.0,0,0,0
        *(uint4*)(sm + SM_RBF + row * 80 + 48) = make_uint4(0, 0, 0, 0);
    }

    // per-thread edge columns (packed with edge id, no dependent gather)
    int colp[4];
    #pragma unroll
    for (int nt = 0; nt < 4; ++nt) colp[nt] = pc[p0 + nt * 16 + l15].y;

    // GEMM1 A-frags (Wf1T) and GEMM2 ks=0 A-frags (Wf2T): wave owns tiles 2w,2w+1
    short8 a1[2], acur[2];
    #pragma unroll
    for (int mt = 0; mt < 2; ++mt) {
        a1[mt]   = *(const short8*)(P1 + ((2 * w + mt) * 64 + l) * 8);
        acur[mt] = *(const short8*)(P2 + ((2 * w + mt) * 64 + l) * 8);
    }

    __syncthreads();

    f32x4 acc[2][4];   // [mt][nt]
    #pragma unroll
    for (int mt = 0; mt < 2; ++mt)
        #pragma unroll
        for (int nt = 0; nt < 4; ++nt) acc[mt][nt] = (f32x4)0.0f;

    // GEMM1: one K=32 step; B = rbfT from LDS (stride 80B)
    #pragma unroll
    for (int nt = 0; nt < 4; ++nt) {
        short8 bfr = *(const short8*)(sm + SM_RBF + (nt * 16 + l15) * 80 + l4 * 16);
        #pragma unroll
        for (int mt = 0; mt < 2; ++mt)
            acc[mt][nt] = __builtin_amdgcn_mfma_f32_16x16x32_bf16(a1[mt], bfr, acc[mt][nt], 0, 0, 0);
    }

    // silu -> hid bf16, XOR-swizzled, b64 stores
    #pragma unroll
    for (int mt = 0; mt < 2; ++mt) {
        const int hc0 = w * 32 + mt * 16 + l4 * 4;
        #pragma unroll
        for (int nt = 0; nt < 4; ++nt) {
            const int row = nt * 16 + l15;
            unsigned int pk0 = cvt_pk(silu_f(acc[mt][nt][0]), silu_f(acc[mt][nt][1]));
            unsigned int pk1 = cvt_pk(silu_f(acc[mt][nt][2]), silu_f(acc[mt][nt][3]));
            *(uint2*)(sm + SM_HID + row * 512 +
                      (((hc0 >> 3) ^ (row & 7)) << 4) + (hc0 & 7) * 2) =
                make_uint2(pk0, pk1);
        }
    }
    __syncthreads();

    // GEMM2: filtT = Wf2T.hiddenT (1-deep A-frag prefetch)
    #pragma unroll
    for (int mt = 0; mt < 2; ++mt)
        #pragma unroll
        for (int nt = 0; nt < 4; ++nt) acc[mt][nt] = (f32x4)0.0f;

    for (int ks = 0; ks < 8; ++ks) {
        short8 anext[2];
        if (ks < 7) {
            #pragma unroll
            for (int mt = 0; mt < 2; ++mt)
                anext[mt] = *(const short8*)(P2 + (((ks + 1) * 16 + 2 * w + mt) * 64 + l) * 8);
        }
        #pragma unroll
        for (int nt = 0; nt < 4; ++nt) {
            const int row = nt * 16 + l15;
            short8 bfh = *(const short8*)(sm + SM_HID + row * 512 +
                            ((((ks << 2) + l4) ^ (row & 7)) << 4));
            #pragma unroll
            for (int mt = 0; mt < 2; ++mt)
                acc[mt][nt] = __builtin_amdgcn_mfma_f32_16x16x32_bf16(acur[mt], bfh, acc[mt][nt], 0, 0, 0);
        }
        if (ks < 7) {
            #pragma unroll
            for (int mt = 0; mt < 2; ++mt) acur[mt] = anext[mt];
        }
    }

    // bf16 x gather (5MB table, ~L2/L3 resident)
    uint2 xv[2][4];
    #pragma unroll
    for (int mt = 0; mt < 2; ++mt) {
        const int fc0 = w * 32 + mt * 16 + l4 * 4;
        #pragma unroll
        for (int nt = 0; nt < 4; ++nt)
            xv[mt][nt] = *(const uint2*)(xb + (size_t)colp[nt] * HDIM + fc0);
    }

    f32x4 bc2[2];
    #pragma unroll
    for (int mt = 0; mt < 2; ++mt)
        bc2[mt] = *(const f32x4*)(bf2 + w * 32 + mt * 16 + l4 * 4);

    __syncthreads();   // all hid reads done -> msg overlay

    // msg = (filt+bias)*x -> bf16 LDS, single pass over all 64 rows
    #pragma unroll
    for (int mt = 0; mt < 2; ++mt) {
        const int fc0 = w * 32 + mt * 16 + l4 * 4;
        #pragma unroll
        for (int nt = 0; nt < 4; ++nt) {
            const int row = nt * 16 + l15;
            f32x4 m = (acc[mt][nt] + bc2[mt]) * bf4_to_f32(xv[mt][nt]);
            *(uint2*)(sm + SM_HID + row * 512 +
                      (((fc0 >> 3) ^ (row & 7)) << 4) + (fc0 & 7) * 2) =
                make_uint2(cvt_pk(m[0], m[1]), cvt_pk(m[2], m[3]));
        }
    }
    __syncthreads();

    // segmented reduce: 512 threads = 256 cols x 2 halves of 32 rows.
    // 8-deep batched LDS loads; boundary segment merged via LDS stash.
    {
        const int col = t & 255;
        const int h   = t >> 8;
        const int base = h * 32;
        int* stash_nid   = (int*)(sm + SM_RBF);            // 1 KB (rbf dead)
        float* stash_sum = (float*)(sm + SM_RBF + 1024);   // 1 KB

        float sum = 0.0f;
        int cur = nid_s[base];
        int fnid = 0; float fsum = 0.0f;
        bool held = false;

        #pragma unroll
        for (int c = 0; c < 4; ++c) {
            float v[8];
            #pragma unroll
            for (int i = 0; i < 8; ++i) {
                const int pos = base + c * 8 + i;
                unsigned short u = *(const unsigned short*)(sm + SM_HID + pos * 512 +
                                    (((col >> 3) ^ (pos & 7)) << 4) + (col & 7) * 2);
                union { unsigned int ii; float f; } cv; cv.ii = ((unsigned int)u) << 16;
                v[i] = cv.f;
            }
            #pragma unroll
            for (int i = 0; i < 8; ++i) {
                const int nid = nid_s[base + c * 8 + i];
                if (nid != cur) {
                    if (h == 1 && !held) { fnid = cur; fsum = sum; held = true; }
                    else atomicAdd(&agg[(size_t)cur * HDIM + col], sum);
                    sum = 0.0f; cur = nid;
                }
                sum += v[i];
            }
        }
        if (h == 0) {
            stash_nid[col] = cur; stash_sum[col] = sum;
        } else {
            if (!held) { fnid = cur; fsum = sum; }
            else atomicAdd(&agg[(size_t)cur * HDIM + col], sum);
        }
        __syncthreads();
        if (h == 1) {
            int n0 = stash_nid[col]; float s0 = stash_sum[col];
            if (n0 == fnid) {
                atomicAdd(&agg[(size_t)n0 * HDIM + col], s0 + fsum);
            } else {
                atomicAdd(&agg[(size_t)n0 * HDIM + col], s0);
                atomicAdd(&agg[(size_t)fnid * HDIM + col], fsum);
            }
        }
    }
}

// ---------------------------------------------------------------------------
// Node kernel (r11/r14 configuration — best measured): 64 rows/block,
// 512 threads (8 waves, wave owns 32 cols), both GEMMs swapped, fused BN
// partials. LDS 32KB.
// ---------------------------------------------------------------------------
__global__ __launch_bounds__(512, 2) void node_kernel(
    const float* __restrict__ agg, const float* __restrict__ bu1,
    const float* __restrict__ bu2,
    const unsigned short* __restrict__ Pu1, const unsigned short* __restrict__ Pu2,
    float* __restrict__ hout, float* __restrict__ sums)
{
    __shared__ char sm[32768];    // [64 nodes][256] bf16, XOR-swizzled
    const int t  = threadIdx.x;
    const int r0 = blockIdx.x * 64;
    const int l = t & 63, w = t >> 6;        // 8 waves
    const int l15 = l & 15, l4 = l >> 4;

    // stage agg -> LDS bf16 (8 threads/row, 8 float4 each)
    {
        const int row = t & 63, q = t >> 6;
        const bool valid = (r0 + row) < N_NODES;
        const float4* src = (const float4*)(agg + (size_t)(r0 + row) * HDIM) + q * 8;
        #pragma unroll
        for (int i = 0; i < 8; ++i) {
            float4 v = valid ? src[i] : make_float4(0.f, 0.f, 0.f, 0.f);
            const int c0 = q * 32 + i * 4;
            *(uint2*)(sm + row * 512 + (((c0 >> 3) ^ (row & 7)) << 4) + (c0 & 7) * 2) =
                make_uint2(cvt_pk(v.x, v.y), cvt_pk(v.z, v.w));
        }
    }

    short8 acur[2];
    #pragma unroll
    for (int mt = 0; mt < 2; ++mt)
        acur[mt] = *(const short8*)(Pu1 + ((2 * w + mt) * 64 + l) * 8);

    __syncthreads();

    f32x4 acc[2][4];
    #pragma unroll
    for (int mt = 0; mt < 2; ++mt)
        #pragma unroll
        for (int nt = 0; nt < 4; ++nt) acc[mt][nt] = (f32x4)0.0f;

    // GEMM1': midT = Wu1T.aggT
    for (int ks = 0; ks < 8; ++ks) {
        short8 anext[2];
        if (ks < 7) {
            #pragma unroll
            for (int mt = 0; mt < 2; ++mt)
                anext[mt] = *(const short8*)(Pu1 + (((ks + 1) * 16 + 2 * w + mt) * 64 + l) * 8);
        }
        #pragma unroll
        for (int nt = 0; nt < 4; ++nt) {
            const int row = nt * 16 + l15;
            short8 bfa = *(const short8*)(sm + row * 512 +
                            ((((ks << 2) + l4) ^ (row & 7)) << 4));
            #pragma unroll
            for (int mt = 0; mt < 2; ++mt)
                acc[mt][nt] = __builtin_amdgcn_mfma_f32_16x16x32_bf16(acur[mt], bfa, acc[mt][nt], 0, 0, 0);
        }
        if (ks < 7) {
            #pragma unroll
            for (int mt = 0; mt < 2; ++mt) acur[mt] = anext[mt];
        }
    }
    __syncthreads();   // all reads done; overwrite with mid

    #pragma unroll
    for (int mt = 0; mt < 2; ++mt)
        acur[mt] = *(const short8*)(Pu2 + ((2 * w + mt) * 64 + l) * 8);

    // mid = silu(acc + bu1) -> LDS (b64 stores)
    #pragma unroll
    for (int mt = 0; mt < 2; ++mt) {
        const int mc0 = w * 32 + mt * 16 + l4 * 4;
        f32x4 b4 = *(const f32x4*)(bu1 + mc0);
        #pragma unroll
        for (int nt = 0; nt < 4; ++nt) {
            const int row = nt * 16 + l15;
            unsigned int pk0 = cvt_pk(silu_f(acc[mt][nt][0] + b4[0]), silu_f(acc[mt][nt][1] + b4[1]));
            unsigned int pk1 = cvt_pk(silu_f(acc[mt][nt][2] + b4[2]), silu_f(acc[mt][nt][3] + b4[3]));
            *(uint2*)(sm + row * 512 + (((mc0 >> 3) ^ (row & 7)) << 4) + (mc0 & 7) * 2) =
                make_uint2(pk0, pk1);
            acc[mt][nt] = (f32x4)0.0f;
        }
    }
    __syncthreads();

    // GEMM2': hT = Wu2T.midT
    for (int ks = 0; ks < 8; ++ks) {
        short8 anext[2];
        if (ks < 7) {
            #pragma unroll
            for (int mt = 0; mt < 2; ++mt)
                anext[mt] = *(const short8*)(Pu2 + (((ks + 1) * 16 + 2 * w + mt) * 64 + l) * 8);
        }
        #pragma unroll
        for (int nt = 0; nt < 4; ++nt) {
            const int row = nt * 16 + l15;
            short8 bfm = *(const short8*)(sm + row * 512 +
                            ((((ks << 2) + l4) ^ (row & 7)) << 4));
            #pragma unroll
            for (int mt = 0; mt < 2; ++mt)
                acc[mt][nt] = __builtin_amdgcn_mfma_f32_16x16x32_bf16(acur[mt], bfm, acc[mt][nt], 0, 0, 0);
        }
        if (ks < 7) {
            #pragma unroll
            for (int mt = 0; mt < 2; ++mt) acur[mt] = anext[mt];
        }
    }

    // epilogue: float4 h stores + BN partials
    #pragma unroll
    for (int mt = 0; mt < 2; ++mt) {
        const int hc0 = w * 32 + mt * 16 + l4 * 4;
        f32x4 b4 = *(const f32x4*)(bu2 + hc0);
        f32x4 s = (f32x4)0.0f, s2 = (f32x4)0.0f;
        #pragma unroll
        for (int nt = 0; nt < 4; ++nt) {
            const int gr = r0 + nt * 16 + l15;
            if (gr < N_NODES) {
                f32x4 hv = acc[mt][nt] + b4;
                *(f32x4*)(hout + (size_t)gr * HDIM + hc0) = hv;
                s += hv; s2 += hv * hv;
            }
        }
        #pragma unroll
        for (int off = 1; off < 16; off <<= 1) {
            #pragma unroll
            for (int r = 0; r < 4; ++r) {
                s[r]  += __shfl_xor(s[r], off);
                s2[r] += __shfl_xor(s2[r], off);
            }
        }
        if (l15 == 0) {
            #pragma unroll
            for (int r = 0; r < 4; ++r) {
                atomicAdd(&sums[hc0 + r], s[r]);
                atomicAdd(&sums[HDIM + hc0 + r], s2[r]);
            }
        }
    }
}

// ---------------------------------------------------------------------------
__global__ __launch_bounds__(256) void final_kernel(
    const float* __restrict__ x, const float* __restrict__ sums,
    const float* __restrict__ gamma, const float* __restrict__ beta,
    float* __restrict__ out)
{
    const int i4 = blockIdx.x * 256 + threadIdx.x;   // float4 index
    const int j  = (i4 & 63) * 4;
    f32x4 mean = *(const f32x4*)(sums + j) * (1.0f / N_NODES);
    f32x4 s2   = *(const f32x4*)(sums + HDIM + j) * (1.0f / N_NODES);
    f32x4 g    = *(const f32x4*)(gamma + j);
    f32x4 b    = *(const f32x4*)(beta + j);
    f32x4 hv   = ((f32x4*)out)[i4];
    f32x4 xv   = ((const f32x4*)x)[i4];
    f32x4 var  = s2 - mean * mean;
    f32x4 inv;
    #pragma unroll
    for (int r = 0; r < 4; ++r) inv[r] = rsqrtf(var[r] + BN_EPS);
    ((f32x4*)out)[i4] = xv + g * (hv - mean) * inv + b;
}

extern "C" void kernel_launch(void* const* d_in, const int* in_sizes, int n_in,
                              void* d_out, int out_size, void* d_ws, size_t ws_size,
                              hipStream_t stream) {
    const float* x     = (const float*)d_in[0];
    const float* rbf   = (const float*)d_in[1];
    const int*   ei    = (const int*)d_in[2];
    const float* Wf1   = (const float*)d_in[3];
    const float* bf1   = (const float*)d_in[4];
    const float* Wf2   = (const float*)d_in[5];
    const float* bf2   = (const float*)d_in[6];
    const float* Wu1   = (const float*)d_in[7];
    const float* bu1   = (const float*)d_in[8];
    const float* Wu2   = (const float*)d_in[9];
    const float* bu2   = (const float*)d_in[10];
    const float* gamma = (const float*)d_in[11];
    const float* beta  = (const float*)d_in[12];
    float* out = (float*)d_out;

    char* ws = (char*)d_ws;
    float* agg     = (float*)(ws);                            // 10,240,000 B
    float* sums    = (float*)(ws + 10240000);                 // 2,048 B
    int*   cnt     = (int*)(ws + 10242048);                   // 40,960 B
    int*   nodepos = (int*)(ws + 10283008);                   // 1,280,000 B
    unsigned short* Pf2 = (unsigned short*)(ws + 11563008);   // 131,072 B
    unsigned short* Pu1 = (unsigned short*)(ws + 11694080);   // 131,072 B
    unsigned short* Pu2 = (unsigned short*)(ws + 11825152);   // 131,072 B
    unsigned short* P1  = (unsigned short*)(ws + 11956224);   // 16,384 B

    // d_out scratch (fully overwritten by node_kernel afterwards):
    //   [0, 5.12MB): bf16 x    [5.12MB, 7.68MB): packed {edge, col} int2
    unsigned short* xb = (unsigned short*)d_out;
    int2* pc = (int2*)((char*)d_out + 5120000);

    // one memset covers agg + sums + cnt (contiguous)
    hipMemsetAsync(agg, 0, 10283008, stream);

    prep_hist_kernel<<<3300, 256, 0, stream>>>(Wf2, Wu1, Wu2, Wf1, bf1, ei, x,
                                               Pf2, Pu1, Pu2, P1, cnt, xb);
    scan_kernel<<<1, 256, 0, stream>>>(cnt);
    fill_kernel<<<E_EDGES / 256, 256, 0, stream>>>(ei, ei + E_EDGES, cnt,
                                                   pc, nodepos);

    edge_kernel<<<E_EDGES / 64, 512, 0, stream>>>(
        rbf, pc, nodepos, P1, Pf2, bf2, xb, agg);
    node_kernel<<<(N_NODES + 63) / 64, 512, 0, stream>>>(
        agg, bu1, bu2, Pu1, Pu2, out, sums);
    final_kernel<<<(N_NODES * HDIM / 4) / 256, 256, 0, stream>>>(
        x, sums, gamma, beta, out);
}

// Round 16
// 182.103 us; speedup vs baseline: 1.1243x; 1.0025x over previous
//
#include <hip/hip_runtime.h>

#define N_NODES 10000
#define E_EDGES 320000
#define HDIM    256
#define NG      20
#define BN_EPS  1e-5f

typedef __attribute__((ext_vector_type(8))) short short8;
typedef __attribute__((ext_vector_type(4))) float f32x4;

__device__ __forceinline__ float silu_f(float v) {
    float e = __expf(-v);
    return v * __builtin_amdgcn_rcpf(1.0f + e);
}

__device__ __forceinline__ unsigned int cvt_pk(float lo, float hi) {
    unsigned int r;
    asm("v_cvt_pk_bf16_f32 %0, %1, %2" : "=v"(r) : "v"(lo), "v"(hi));
    return r;
}

__device__ __forceinline__ unsigned short f2bf(float f) {
    union { float f; unsigned int u; } v; v.f = f;
    unsigned int r = v.u + 0x7fffu + ((v.u >> 16) & 1u);   // RNE
    return (unsigned short)(r >> 16);
}

__device__ __forceinline__ f32x4 bf4_to_f32(uint2 u) {
    union { unsigned int i; float f; } a, b, c, d;
    a.i = u.x << 16; b.i = u.x & 0xFFFF0000u;
    c.i = u.y << 16; d.i = u.y & 0xFFFF0000u;
    return (f32x4){a.f, b.f, c.f, d.f};
}

// ---------------------------------------------------------------------------
// Fused prep: weight packing + edge histogram + x -> bf16 cast.
// ---------------------------------------------------------------------------
__global__ __launch_bounds__(256) void prep_hist_kernel(
    const float* __restrict__ Wf2, const float* __restrict__ Wu1,
    const float* __restrict__ Wu2, const float* __restrict__ Wf1,
    const float* __restrict__ bf1, const int* __restrict__ ei_row,
    const float* __restrict__ x,
    unsigned short* __restrict__ Pf2, unsigned short* __restrict__ Pu1,
    unsigned short* __restrict__ Pu2, unsigned short* __restrict__ P1,
    int* __restrict__ cnt, unsigned short* __restrict__ xb)
{
    const int bx = blockIdx.x;
    if (bx >= 2050) {
        const int idx = ((bx - 2050) * 256 + threadIdx.x) * 8;
        const float4* s = (const float4*)(x + idx);
        float4 a = s[0], b = s[1];
        *(uint4*)(xb + idx) = make_uint4(cvt_pk(a.x, a.y), cvt_pk(a.z, a.w),
                                         cvt_pk(b.x, b.y), cvt_pk(b.z, b.w));
        return;
    }
    if (bx >= 800) {
        int e = (bx - 800) * 256 + threadIdx.x;
        atomicAdd(&cnt[ei_row[e]], 1);
        return;
    }
    int tid = bx * 256 + threadIdx.x;
    if (tid < 196608) {
        int which = tid >> 16, local = tid & 65535;
        const float* W = (which == 0) ? Wf2 : (which == 1) ? Wu1 : Wu2;
        unsigned short* P = (which == 0) ? Pf2 : (which == 1) ? Pu1 : Pu2;
        int j = local & 7, lane = (local >> 3) & 63;
        int ntile = (local >> 9) & 15, kstep = local >> 13;
        int k = kstep * 32 + (lane >> 4) * 8 + j;
        int n = ntile * 16 + (lane & 15);
        P[local] = f2bf(W[k * 256 + n]);
    } else {
        int local = tid - 196608;   // 0..8191
        int j = local & 7, lane = (local >> 3) & 63, ntile = local >> 9;
        int k = (lane >> 4) * 8 + j;
        int n = ntile * 16 + (lane & 15);
        float v = (k < NG) ? Wf1[k * 256 + n] : (k == NG ? bf1[n] : 0.0f);
        P1[local] = f2bf(v);
    }
}

// ---------------------------------------------------------------------------
// CSR build: scan (1024 threads, 10 counters each) + fill (single int4 store)
// ---------------------------------------------------------------------------
__global__ __launch_bounds__(1024) void scan_kernel(int* __restrict__ cnt) {
    __shared__ int tot[1024];
    const int t = threadIdx.x;
    int loc[10];
    int s = 0;
    #pragma unroll
    for (int i = 0; i < 10; ++i) { loc[i] = cnt[t * 10 + i]; s += loc[i]; }
    tot[t] = s;
    __syncthreads();
    for (int off = 1; off < 1024; off <<= 1) {
        int u = (t >= off) ? tot[t - off] : 0;
        __syncthreads();
        tot[t] += u;
        __syncthreads();
    }
    int pre = tot[t] - s;
    #pragma unroll
    for (int i = 0; i < 10; ++i) { int v = loc[i]; cnt[t * 10 + i] = pre; pre += v; }
}

__global__ __launch_bounds__(256) void fill_kernel(const int* __restrict__ ei_row,
                                                   const int* __restrict__ ei_col,
                                                   int* __restrict__ cnt,
                                                   int4* __restrict__ pc4) {
    int e = blockIdx.x * 256 + threadIdx.x;
    int r = ei_row[e];
    int c = ei_col[e];
    int pos = atomicAdd(&cnt[r], 1);
    pc4[pos] = make_int4(e, c, r, 0);   // one 16B line-write per edge
}

// ---------------------------------------------------------------------------
// Edge kernel (r13/r15 configuration — best measured): 64 CSR-ordered edges /
// block, 8 waves (512 thr), 3 blocks/CU.
// GEMM1 (swapped): hiddenT = Wf1T.rbfT; rbf staged once in LDS (80B rows).
// GEMM2 (swapped): filtT = Wf2T.hiddenT; 1-deep A-frag prefetch from L2.
// msg = (filt+bf2)*xb[col] stored bf16 (single pass, all 64 rows).
// Reduce: 512 threads = 256 cols x 2 halves of 32 rows; 8-deep batched LDS
// loads; boundary merged via LDS stash; contiguous per-node-row atomics.
// ---------------------------------------------------------------------------
#define SM_NID 0        // 64 int (256 B)
#define SM_RBF 256      // [64][40] ushort rows of 80 B (5120 B); stash overlay
#define SM_HID 5376     // 32768 B: hid bf16 [64][256] swz / msg bf16 overlay
#define SM_TOT 38144

__global__ __launch_bounds__(512, 6) void edge_kernel(
    const float* __restrict__ rbf, const int4* __restrict__ pc4,
    const unsigned short* __restrict__ P1, const unsigned short* __restrict__ P2,
    const float* __restrict__ bf2, const unsigned short* __restrict__ xb,
    float* __restrict__ agg)
{
    __shared__ char sm[SM_TOT];
    int* nid_s = (int*)(sm + SM_NID);

    const int t = threadIdx.x;
    int blk = blockIdx.x;
    blk = (blk & 7) * 625 + (blk >> 3);   // XCD swizzle (5000 = 8*625, bijective)
    const int p0 = blk * 64;
    const int l = t & 63, w = t >> 6;
    const int l15 = l & 15, l4 = l >> 4;

    if (t < 64) nid_s[t] = pc4[p0 + t].z;
    // rbf -> LDS bf16, 80 B rows; k=20 bias row (1.0), 21..31 zero
    if (t < 128) {
        const int row = t >> 1, half = t & 1;
        const float* rp = rbf + (size_t)pc4[p0 + row].x * NG + half * 10;
        float v[10];
        if (half == 0) {
            float4 a = *(const float4*)rp, b = *(const float4*)(rp + 4);
            float2 c = *(const float2*)(rp + 8);
            v[0]=a.x; v[1]=a.y; v[2]=a.z; v[3]=a.w; v[4]=b.x;
            v[5]=b.y; v[6]=b.z; v[7]=b.w; v[8]=c.x; v[9]=c.y;
        } else {
            float2 a = *(const float2*)rp;
            float4 b = *(const float4*)(rp + 2), c = *(const float4*)(rp + 6);
            v[0]=a.x; v[1]=a.y; v[2]=b.x; v[3]=b.y; v[4]=b.z;
            v[5]=b.w; v[6]=c.x; v[7]=c.y; v[8]=c.z; v[9]=c.w;
        }
        unsigned int* dst = (unsigned int*)(sm + SM_RBF + row * 80 + half * 20);
        #pragma unroll
        for (int i = 0; i < 5; ++i) dst[i] = cvt_pk(v[2*i], v[2*i+1]);
    } else if (t < 192) {
        const int row = t - 128;
        *(unsigned long long*)(sm + SM_RBF + row * 80 + 40) = 0x3F80ull; // 1.0,0,0,0
        *(uint4*)(sm + SM_RBF + row * 80 + 48) = make_uint4(0, 0, 0, 0);
    }

    // per-thread edge columns (same 16B line as e/row: L1 hits)
    int colp[4];
    #pragma unroll
    for (int nt = 0; nt < 4; ++nt) colp[nt] = pc4[p0 + nt * 16 + l15].y;

    // GEMM1 A-frags (Wf1T) and GEMM2 ks=0 A-frags (Wf2T): wave owns tiles 2w,2w+1
    short8 a1[2], acur[2];
    #pragma unroll
    for (int mt = 0; mt < 2; ++mt) {
        a1[mt]   = *(const short8*)(P1 + ((2 * w + mt) * 64 + l) * 8);
        acur[mt] = *(const short8*)(P2 + ((2 * w + mt) * 64 + l) * 8);
    }

    __syncthreads();

    f32x4 acc[2][4];   // [mt][nt]
    #pragma unroll
    for (int mt = 0; mt < 2; ++mt)
        #pragma unroll
        for (int nt = 0; nt < 4; ++nt) acc[mt][nt] = (f32x4)0.0f;

    // GEMM1: one K=32 step; B = rbfT from LDS (stride 80B)
    #pragma unroll
    for (int nt = 0; nt < 4; ++nt) {
        short8 bfr = *(const short8*)(sm + SM_RBF + (nt * 16 + l15) * 80 + l4 * 16);
        #pragma unroll
        for (int mt = 0; mt < 2; ++mt)
            acc[mt][nt] = __builtin_amdgcn_mfma_f32_16x16x32_bf16(a1[mt], bfr, acc[mt][nt], 0, 0, 0);
    }

    // silu -> hid bf16, XOR-swizzled, b64 stores
    #pragma unroll
    for (int mt = 0; mt < 2; ++mt) {
        const int hc0 = w * 32 + mt * 16 + l4 * 4;
        #pragma unroll
        for (int nt = 0; nt < 4; ++nt) {
            const int row = nt * 16 + l15;
            unsigned int pk0 = cvt_pk(silu_f(acc[mt][nt][0]), silu_f(acc[mt][nt][1]));
            unsigned int pk1 = cvt_pk(silu_f(acc[mt][nt][2]), silu_f(acc[mt][nt][3]));
            *(uint2*)(sm + SM_HID + row * 512 +
                      (((hc0 >> 3) ^ (row & 7)) << 4) + (hc0 & 7) * 2) =
                make_uint2(pk0, pk1);
        }
    }
    __syncthreads();

    // GEMM2: filtT = Wf2T.hiddenT (1-deep A-frag prefetch)
    #pragma unroll
    for (int mt = 0; mt < 2; ++mt)
        #pragma unroll
        for (int nt = 0; nt < 4; ++nt) acc[mt][nt] = (f32x4)0.0f;

    for (int ks = 0; ks < 8; ++ks) {
        short8 anext[2];
        if (ks < 7) {
            #pragma unroll
            for (int mt = 0; mt < 2; ++mt)
                anext[mt] = *(const short8*)(P2 + (((ks + 1) * 16 + 2 * w + mt) * 64 + l) * 8);
        }
        #pragma unroll
        for (int nt = 0; nt < 4; ++nt) {
            const int row = nt * 16 + l15;
            short8 bfh = *(const short8*)(sm + SM_HID + row * 512 +
                            ((((ks << 2) + l4) ^ (row & 7)) << 4));
            #pragma unroll
            for (int mt = 0; mt < 2; ++mt)
                acc[mt][nt] = __builtin_amdgcn_mfma_f32_16x16x32_bf16(acur[mt], bfh, acc[mt][nt], 0, 0, 0);
        }
        if (ks < 7) {
            #pragma unroll
            for (int mt = 0; mt < 2; ++mt) acur[mt] = anext[mt];
        }
    }

    // bf16 x gather (5MB table, ~L2/L3 resident)
    uint2 xv[2][4];
    #pragma unroll
    for (int mt = 0; mt < 2; ++mt) {
        const int fc0 = w * 32 + mt * 16 + l4 * 4;
        #pragma unroll
        for (int nt = 0; nt < 4; ++nt)
            xv[mt][nt] = *(const uint2*)(xb + (size_t)colp[nt] * HDIM + fc0);
    }

    f32x4 bc2[2];
    #pragma unroll
    for (int mt = 0; mt < 2; ++mt)
        bc2[mt] = *(const f32x4*)(bf2 + w * 32 + mt * 16 + l4 * 4);

    __syncthreads();   // all hid reads done -> msg overlay

    // msg = (filt+bias)*x -> bf16 LDS, single pass over all 64 rows
    #pragma unroll
    for (int mt = 0; mt < 2; ++mt) {
        const int fc0 = w * 32 + mt * 16 + l4 * 4;
        #pragma unroll
        for (int nt = 0; nt < 4; ++nt) {
            const int row = nt * 16 + l15;
            f32x4 m = (acc[mt][nt] + bc2[mt]) * bf4_to_f32(xv[mt][nt]);
            *(uint2*)(sm + SM_HID + row * 512 +
                      (((fc0 >> 3) ^ (row & 7)) << 4) + (fc0 & 7) * 2) =
                make_uint2(cvt_pk(m[0], m[1]), cvt_pk(m[2], m[3]));
        }
    }
    __syncthreads();

    // segmented reduce: 512 threads = 256 cols x 2 halves of 32 rows.
    // 8-deep batched LDS loads; boundary segment merged via LDS stash.
    {
        const int col = t & 255;
        const int h   = t >> 8;
        const int base = h * 32;
        int* stash_nid   = (int*)(sm + SM_RBF);            // 1 KB (rbf dead)
        float* stash_sum = (float*)(sm + SM_RBF + 1024);   // 1 KB

        float sum = 0.0f;
        int cur = nid_s[base];
        int fnid = 0; float fsum = 0.0f;
        bool held = false;

        #pragma unroll
        for (int c = 0; c < 4; ++c) {
            float v[8];
            #pragma unroll
            for (int i = 0; i < 8; ++i) {
                const int pos = base + c * 8 + i;
                unsigned short u = *(const unsigned short*)(sm + SM_HID + pos * 512 +
                                    (((col >> 3) ^ (pos & 7)) << 4) + (col & 7) * 2);
                union { unsigned int ii; float f; } cv; cv.ii = ((unsigned int)u) << 16;
                v[i] = cv.f;
            }
            #pragma unroll
            for (int i = 0; i < 8; ++i) {
                const int nid = nid_s[base + c * 8 + i];
                if (nid != cur) {
                    if (h == 1 && !held) { fnid = cur; fsum = sum; held = true; }
                    else atomicAdd(&agg[(size_t)cur * HDIM + col], sum);
                    sum = 0.0f; cur = nid;
                }
                sum += v[i];
            }
        }
        if (h == 0) {
            stash_nid[col] = cur; stash_sum[col] = sum;
        } else {
            if (!held) { fnid = cur; fsum = sum; }
            else atomicAdd(&agg[(size_t)cur * HDIM + col], sum);
        }
        __syncthreads();
        if (h == 1) {
            int n0 = stash_nid[col]; float s0 = stash_sum[col];
            if (n0 == fnid) {
                atomicAdd(&agg[(size_t)n0 * HDIM + col], s0 + fsum);
            } else {
                atomicAdd(&agg[(size_t)n0 * HDIM + col], s0);
                atomicAdd(&agg[(size_t)fnid * HDIM + col], fsum);
            }
        }
    }
}

// ---------------------------------------------------------------------------
// Node kernel (r11/r15 configuration — best measured): 64 rows/block,
// 512 threads (8 waves, wave owns 32 cols), both GEMMs swapped, fused BN
// partials. LDS 32KB.
// ---------------------------------------------------------------------------
__global__ __launch_bounds__(512, 2) void node_kernel(
    const float* __restrict__ agg, const float* __restrict__ bu1,
    const float* __restrict__ bu2,
    const unsigned short* __restrict__ Pu1, const unsigned short* __restrict__ Pu2,
    float* __restrict__ hout, float* __restrict__ sums)
{
    __shared__ char sm[32768];    // [64 nodes][256] bf16, XOR-swizzled
    const int t  = threadIdx.x;
    const int r0 = blockIdx.x * 64;
    const int l = t & 63, w = t >> 6;        // 8 waves
    const int l15 = l & 15, l4 = l >> 4;

    // stage agg -> LDS bf16 (8 threads/row, 8 float4 each)
    {
        const int row = t & 63, q = t >> 6;
        const bool valid = (r0 + row) < N_NODES;
        const float4* src = (const float4*)(agg + (size_t)(r0 + row) * HDIM) + q * 8;
        #pragma unroll
        for (int i = 0; i < 8; ++i) {
            float4 v = valid ? src[i] : make_float4(0.f, 0.f, 0.f, 0.f);
            const int c0 = q * 32 + i * 4;
            *(uint2*)(sm + row * 512 + (((c0 >> 3) ^ (row & 7)) << 4) + (c0 & 7) * 2) =
                make_uint2(cvt_pk(v.x, v.y), cvt_pk(v.z, v.w));
        }
    }

    short8 acur[2];
    #pragma unroll
    for (int mt = 0; mt < 2; ++mt)
        acur[mt] = *(const short8*)(Pu1 + ((2 * w + mt) * 64 + l) * 8);

    __syncthreads();

    f32x4 acc[2][4];
    #pragma unroll
    for (int mt = 0; mt < 2; ++mt)
        #pragma unroll
        for (int nt = 0; nt < 4; ++nt) acc[mt][nt] = (f32x4)0.0f;

    // GEMM1': midT = Wu1T.aggT
    for (int ks = 0; ks < 8; ++ks) {
        short8 anext[2];
        if (ks < 7) {
            #pragma unroll
            for (int mt = 0; mt < 2; ++mt)
                anext[mt] = *(const short8*)(Pu1 + (((ks + 1) * 16 + 2 * w + mt) * 64 + l) * 8);
        }
        #pragma unroll
        for (int nt = 0; nt < 4; ++nt) {
            const int row = nt * 16 + l15;
            short8 bfa = *(const short8*)(sm + row * 512 +
                            ((((ks << 2) + l4) ^ (row & 7)) << 4));
            #pragma unroll
            for (int mt = 0; mt < 2; ++mt)
                acc[mt][nt] = __builtin_amdgcn_mfma_f32_16x16x32_bf16(acur[mt], bfa, acc[mt][nt], 0, 0, 0);
        }
        if (ks < 7) {
            #pragma unroll
            for (int mt = 0; mt < 2; ++mt) acur[mt] = anext[mt];
        }
    }
    __syncthreads();   // all reads done; overwrite with mid

    #pragma unroll
    for (int mt = 0; mt < 2; ++mt)
        acur[mt] = *(const short8*)(Pu2 + ((2 * w + mt) * 64 + l) * 8);

    // mid = silu(acc + bu1) -> LDS (b64 stores)
    #pragma unroll
    for (int mt = 0; mt < 2; ++mt) {
        const int mc0 = w * 32 + mt * 16 + l4 * 4;
        f32x4 b4 = *(const f32x4*)(bu1 + mc0);
        #pragma unroll
        for (int nt = 0; nt < 4; ++nt) {
            const int row = nt * 16 + l15;
            unsigned int pk0 = cvt_pk(silu_f(acc[mt][nt][0] + b4[0]), silu_f(acc[mt][nt][1] + b4[1]));
            unsigned int pk1 = cvt_pk(silu_f(acc[mt][nt][2] + b4[2]), silu_f(acc[mt][nt][3] + b4[3]));
            *(uint2*)(sm + row * 512 + (((mc0 >> 3) ^ (row & 7)) << 4) + (mc0 & 7) * 2) =
                make_uint2(pk0, pk1);
            acc[mt][nt] = (f32x4)0.0f;
        }
    }
    __syncthreads();

    // GEMM2': hT = Wu2T.midT
    for (int ks = 0; ks < 8; ++ks) {
        short8 anext[2];
        if (ks < 7) {
            #pragma unroll
            for (int mt = 0; mt < 2; ++mt)
                anext[mt] = *(const short8*)(Pu2 + (((ks + 1) * 16 + 2 * w + mt) * 64 + l) * 8);
        }
        #pragma unroll
        for (int nt = 0; nt < 4; ++nt) {
            const int row = nt * 16 + l15;
            short8 bfm = *(const short8*)(sm + row * 512 +
                            ((((ks << 2) + l4) ^ (row & 7)) << 4));
            #pragma unroll
            for (int mt = 0; mt < 2; ++mt)
                acc[mt][nt] = __builtin_amdgcn_mfma_f32_16x16x32_bf16(acur[mt], bfm, acc[mt][nt], 0, 0, 0);
        }
        if (ks < 7) {
            #pragma unroll
            for (int mt = 0; mt < 2; ++mt) acur[mt] = anext[mt];
        }
    }

    // epilogue: float4 h stores + BN partials
    #pragma unroll
    for (int mt = 0; mt < 2; ++mt) {
        const int hc0 = w * 32 + mt * 16 + l4 * 4;
        f32x4 b4 = *(const f32x4*)(bu2 + hc0);
        f32x4 s = (f32x4)0.0f, s2 = (f32x4)0.0f;
        #pragma unroll
        for (int nt = 0; nt < 4; ++nt) {
            const int gr = r0 + nt * 16 + l15;
            if (gr < N_NODES) {
                f32x4 hv = acc[mt][nt] + b4;
                *(f32x4*)(hout + (size_t)gr * HDIM + hc0) = hv;
                s += hv; s2 += hv * hv;
            }
        }
        #pragma unroll
        for (int off = 1; off < 16; off <<= 1) {
            #pragma unroll
            for (int r = 0; r < 4; ++r) {
                s[r]  += __shfl_xor(s[r], off);
                s2[r] += __shfl_xor(s2[r], off);
            }
        }
        if (l15 == 0) {
            #pragma unroll
            for (int r = 0; r < 4; ++r) {
                atomicAdd(&sums[hc0 + r], s[r]);
                atomicAdd(&sums[HDIM + hc0 + r], s2[r]);
            }
        }
    }
}

// ---------------------------------------------------------------------------
__global__ __launch_bounds__(256) void final_kernel(
    const float* __restrict__ x, const float* __restrict__ sums,
    const float* __restrict__ gamma, const float* __restrict__ beta,
    float* __restrict__ out)
{
    const int i4 = blockIdx.x * 256 + threadIdx.x;   // float4 index
    const int j  = (i4 & 63) * 4;
    f32x4 mean = *(const f32x4*)(sums + j) * (1.0f / N_NODES);
    f32x4 s2   = *(const f32x4*)(sums + HDIM + j) * (1.0f / N_NODES);
    f32x4 g    = *(const f32x4*)(gamma + j);
    f32x4 b    = *(const f32x4*)(beta + j);
    f32x4 hv   = ((f32x4*)out)[i4];
    f32x4 xv   = ((const f32x4*)x)[i4];
    f32x4 var  = s2 - mean * mean;
    f32x4 inv;
    #pragma unroll
    for (int r = 0; r < 4; ++r) inv[r] = rsqrtf(var[r] + BN_EPS);
    ((f32x4*)out)[i4] = xv + g * (hv - mean) * inv + b;
}

extern "C" void kernel_launch(void* const* d_in, const int* in_sizes, int n_in,
                              void* d_out, int out_size, void* d_ws, size_t ws_size,
                              hipStream_t stream) {
    const float* x     = (const float*)d_in[0];
    const float* rbf   = (const float*)d_in[1];
    const int*   ei    = (const int*)d_in[2];
    const float* Wf1   = (const float*)d_in[3];
    const float* bf1   = (const float*)d_in[4];
    const float* Wf2   = (const float*)d_in[5];
    const float* bf2   = (const float*)d_in[6];
    const float* Wu1   = (const float*)d_in[7];
    const float* bu1   = (const float*)d_in[8];
    const float* Wu2   = (const float*)d_in[9];
    const float* bu2   = (const float*)d_in[10];
    const float* gamma = (const float*)d_in[11];
    const float* beta  = (const float*)d_in[12];
    float* out = (float*)d_out;

    char* ws = (char*)d_ws;
    float* agg     = (float*)(ws);                            // 10,240,000 B
    float* sums    = (float*)(ws + 10240000);                 // 2,048 B
    int*   cnt     = (int*)(ws + 10242048);                   // 40,960 B
    unsigned short* Pf2 = (unsigned short*)(ws + 10283008);   // 131,072 B
    unsigned short* Pu1 = (unsigned short*)(ws + 10414080);   // 131,072 B
    unsigned short* Pu2 = (unsigned short*)(ws + 10545152);   // 131,072 B
    unsigned short* P1  = (unsigned short*)(ws + 10676224);   // 16,384 B

    // d_out scratch (fully overwritten by node_kernel afterwards):
    //   [0, 5.12MB): bf16 x    [5.12MB, 10.24MB): packed {e, col, row, 0} int4
    unsigned short* xb = (unsigned short*)d_out;
    int4* pc4 = (int4*)((char*)d_out + 5120000);

    // one memset covers agg + sums + cnt (contiguous)
    hipMemsetAsync(agg, 0, 10283008, stream);

    prep_hist_kernel<<<3300, 256, 0, stream>>>(Wf2, Wu1, Wu2, Wf1, bf1, ei, x,
                                               Pf2, Pu1, Pu2, P1, cnt, xb);
    scan_kernel<<<1, 1024, 0, stream>>>(cnt);
    fill_kernel<<<E_EDGES / 256, 256, 0, stream>>>(ei, ei + E_EDGES, cnt, pc4);

    edge_kernel<<<E_EDGES / 64, 512, 0, stream>>>(
        rbf, pc4, P1, Pf2, bf2, xb, agg);
    node_kernel<<<(N_NODES + 63) / 64, 512, 0, stream>>>(
        agg, bu1, bu2, Pu1, Pu2, out, sums);
    final_kernel<<<(N_NODES * HDIM / 4) / 256, 256, 0, stream>>>(
        x, sums, gamma, beta, out);
}